// Round 2
// baseline (557.765 us; speedup 1.0000x reference)
//
#include <hip/hip_runtime.h>

typedef short bf16x8 __attribute__((ext_vector_type(8)));
typedef float f32x4 __attribute__((ext_vector_type(4)));
typedef unsigned short u16;

#define NB 32
#define LSEQ 577
#define CD 768
#define NH 12
#define HD 64
#define MROWS (NB * LSEQ)  // 18464

__device__ __forceinline__ u16 f2bf(float f) {
  union { float f; unsigned u; } v; v.f = f;
  unsigned u = v.u + 0x7fffu + ((v.u >> 16) & 1u);  // RNE
  return (u16)(u >> 16);
}
__device__ __forceinline__ float bf2f(u16 s) {
  union { unsigned u; float f; } v; v.u = ((unsigned)s) << 16;
  return v.f;
}

// ---------------- K1: QKV GEMM  (M=18464, N=2304, K=768), NT layout ----------
// out[m][n] = sum_k x[m][k] * w_qkv[n][k]; scatter to q/k/v (N,H,L,64) bf16.
__global__ __launch_bounds__(256) void qkv_gemm(
    const float* __restrict__ x, const float* __restrict__ wq,
    u16* __restrict__ qb, u16* __restrict__ kb, u16* __restrict__ vb) {
  __shared__ __align__(16) u16 As[128 * 40];
  __shared__ __align__(16) u16 Bs[128 * 40];
  const int m0 = blockIdx.x * 128;
  const int n0 = blockIdx.y * 128;
  const int t = threadIdx.x;
  const int lane = t & 63, wid = t >> 6;
  const int wm = wid >> 1, wn = wid & 1;
  const int g = lane >> 4, cl = lane & 15;
  const f32x4 fz = {0.f, 0.f, 0.f, 0.f};

  f32x4 acc[4][4];
#pragma unroll
  for (int i = 0; i < 4; ++i)
#pragma unroll
    for (int j = 0; j < 4; ++j) acc[i][j] = fz;

  for (int k0 = 0; k0 < CD; k0 += 32) {
#pragma unroll
    for (int i = 0; i < 4; ++i) {
      int f = t + 256 * i;            // float4 chunk id, 1024 per tile (128 rows x 8 chunks)
      int row = f >> 3;
      int c4 = (f & 7) << 2;
      int gr = m0 + row; gr = gr < MROWS ? gr : MROWS - 1;
      float4 av = *reinterpret_cast<const float4*>(x + (size_t)gr * CD + k0 + c4);
      ushort4 ab;
      ab.x = f2bf(av.x); ab.y = f2bf(av.y); ab.z = f2bf(av.z); ab.w = f2bf(av.w);
      *reinterpret_cast<ushort4*>(&As[row * 40 + c4]) = ab;
      float4 bv = *reinterpret_cast<const float4*>(wq + (size_t)(n0 + row) * CD + k0 + c4);
      ushort4 bb;
      bb.x = f2bf(bv.x); bb.y = f2bf(bv.y); bb.z = f2bf(bv.z); bb.w = f2bf(bv.w);
      *reinterpret_cast<ushort4*>(&Bs[row * 40 + c4]) = bb;
    }
    __syncthreads();
    bf16x8 af[4], bfv[4];
#pragma unroll
    for (int mt = 0; mt < 4; ++mt)
      af[mt] = *reinterpret_cast<const bf16x8*>(&As[(wm * 64 + mt * 16 + cl) * 40 + g * 8]);
#pragma unroll
    for (int nt = 0; nt < 4; ++nt)
      bfv[nt] = *reinterpret_cast<const bf16x8*>(&Bs[(wn * 64 + nt * 16 + cl) * 40 + g * 8]);
#pragma unroll
    for (int mt = 0; mt < 4; ++mt)
#pragma unroll
      for (int nt = 0; nt < 4; ++nt)
        acc[mt][nt] = __builtin_amdgcn_mfma_f32_16x16x32_bf16(af[mt], bfv[nt], acc[mt][nt], 0, 0, 0);
    __syncthreads();
  }

  const int which = n0 / CD;          // uniform per block (128 | 768)
  const int rem0 = n0 % CD;
  u16* dst = which == 0 ? qb : (which == 1 ? kb : vb);
  const float sc = which == 0 ? 0.125f : 1.0f;  // pre-scale q by hd^-0.5
#pragma unroll
  for (int mt = 0; mt < 4; ++mt) {
#pragma unroll
    for (int nt = 0; nt < 4; ++nt) {
      int n = rem0 + wn * 64 + nt * 16 + cl;
      int hh = n >> 6, d = n & 63;
#pragma unroll
      for (int r = 0; r < 4; ++r) {
        int m = m0 + wm * 64 + mt * 16 + g * 4 + r;
        if (m < MROWS) {
          int nb = m / LSEQ, l = m % LSEQ;
          dst[(((size_t)nb * NH + hh) * LSEQ + l) * HD + d] = f2bf(acc[mt][nt][r] * sc);
        }
      }
    }
  }
}

// ---------------- K2: flash attention ---------------------------------------
// block = (qtile, head, batch); 4 waves x 16 q-rows; KV tiles of 64 in LDS.
__global__ __launch_bounds__(256) void attn_fwd(
    const u16* __restrict__ q, const u16* __restrict__ k,
    const u16* __restrict__ v, u16* __restrict__ y) {
  __shared__ __align__(16) u16 Ks[64 * 72];      // [kk][d], pad +8
  __shared__ __align__(16) u16 Vt[64 * 72];      // [d][kk] (V transposed)
  __shared__ __align__(16) u16 Ps[4][16 * 72];   // per-wave P [q][kk]

  const int qtile = blockIdx.x;
  const int h = blockIdx.y;
  const int nb = blockIdx.z;
  const int t = threadIdx.x;
  const int lane = t & 63, wid = t >> 6;
  const int g = lane >> 4, cl = lane & 15;

  const size_t hoff = ((size_t)nb * NH + h) * LSEQ * HD;
  const u16* qh = q + hoff;
  const u16* kh = k + hoff;
  const u16* vh = v + hoff;

  const int qbase = qtile * 64;
  int qrow = qbase + wid * 16 + cl;
  int qrc = qrow < LSEQ ? qrow : LSEQ - 1;
  bf16x8 qf0 = *reinterpret_cast<const bf16x8*>(qh + (size_t)qrc * HD + g * 8);
  bf16x8 qf1 = *reinterpret_cast<const bf16x8*>(qh + (size_t)qrc * HD + 32 + g * 8);

  const f32x4 fz = {0.f, 0.f, 0.f, 0.f};
  float mrow[4], lrow[4];
  f32x4 oacc[4];
#pragma unroll
  for (int r = 0; r < 4; ++r) { mrow[r] = -3.0e38f; lrow[r] = 0.f; }
#pragma unroll
  for (int dt = 0; dt < 4; ++dt) oacc[dt] = fz;

  for (int kv = 0; kv < LSEQ; kv += 64) {
    // stage K (row-major) and V (transposed), zero-fill past L
#pragma unroll
    for (int i = 0; i < 2; ++i) {
      int cidx = t + 256 * i;          // 512 chunks of 8 elems (64 rows x 8 chunks)
      int row = cidx >> 3, d8 = (cidx & 7) << 3;
      int grow = kv + row;
      uint4 kd = {0, 0, 0, 0}, vd = {0, 0, 0, 0};
      if (grow < LSEQ) {
        kd = *reinterpret_cast<const uint4*>(kh + (size_t)grow * HD + d8);
        vd = *reinterpret_cast<const uint4*>(vh + (size_t)grow * HD + d8);
      }
      *reinterpret_cast<uint4*>(&Ks[row * 72 + d8]) = kd;
      const u16* vs = (const u16*)&vd;
#pragma unroll
      for (int j = 0; j < 8; ++j) Vt[(d8 + j) * 72 + row] = vs[j];
    }
    __syncthreads();

    // S = Q K^T (q pre-scaled)
    f32x4 sf[4];
#pragma unroll
    for (int nt = 0; nt < 4; ++nt) {
      bf16x8 b0 = *reinterpret_cast<const bf16x8*>(&Ks[(nt * 16 + cl) * 72 + g * 8]);
      bf16x8 b1 = *reinterpret_cast<const bf16x8*>(&Ks[(nt * 16 + cl) * 72 + 32 + g * 8]);
      f32x4 s = fz;
      s = __builtin_amdgcn_mfma_f32_16x16x32_bf16(qf0, b0, s, 0, 0, 0);
      s = __builtin_amdgcn_mfma_f32_16x16x32_bf16(qf1, b1, s, 0, 0, 0);
      sf[nt] = s;
    }

    // mask + online softmax (row = g*4+r, col = cl within 16-lane group)
    float pm[4] = {-3.0e38f, -3.0e38f, -3.0e38f, -3.0e38f};
#pragma unroll
    for (int nt = 0; nt < 4; ++nt) {
      int kkg = kv + nt * 16 + cl;
      bool ok = kkg < LSEQ;
#pragma unroll
      for (int r = 0; r < 4; ++r) {
        float s = ok ? sf[nt][r] : -3.0e38f;
        sf[nt][r] = s;
        pm[r] = fmaxf(pm[r], s);
      }
    }
#pragma unroll
    for (int off = 1; off < 16; off <<= 1)
#pragma unroll
      for (int r = 0; r < 4; ++r) pm[r] = fmaxf(pm[r], __shfl_xor(pm[r], off));

    float alpha[4], psum[4];
#pragma unroll
    for (int r = 0; r < 4; ++r) {
      float nm = fmaxf(mrow[r], pm[r]);
      alpha[r] = __expf(mrow[r] - nm);
      mrow[r] = nm;
      psum[r] = 0.f;
    }
#pragma unroll
    for (int nt = 0; nt < 4; ++nt)
#pragma unroll
      for (int r = 0; r < 4; ++r) {
        float p = __expf(sf[nt][r] - mrow[r]);   // masked -> exp(-huge) = 0
        sf[nt][r] = p;
        psum[r] += p;
      }
#pragma unroll
    for (int off = 1; off < 16; off <<= 1)
#pragma unroll
      for (int r = 0; r < 4; ++r) psum[r] += __shfl_xor(psum[r], off);
#pragma unroll
    for (int r = 0; r < 4; ++r) lrow[r] = lrow[r] * alpha[r] + psum[r];
#pragma unroll
    for (int dt = 0; dt < 4; ++dt)
#pragma unroll
      for (int r = 0; r < 4; ++r) oacc[dt][r] *= alpha[r];

    // P -> LDS (transpose C-layout -> A-layout)
#pragma unroll
    for (int nt = 0; nt < 4; ++nt)
#pragma unroll
      for (int r = 0; r < 4; ++r)
        Ps[wid][(g * 4 + r) * 72 + nt * 16 + cl] = f2bf(sf[nt][r]);
    __syncthreads();

    // O += P V
#pragma unroll
    for (int kc = 0; kc < 2; ++kc) {
      bf16x8 pa = *reinterpret_cast<const bf16x8*>(&Ps[wid][cl * 72 + kc * 32 + g * 8]);
#pragma unroll
      for (int dt = 0; dt < 4; ++dt) {
        bf16x8 vbf = *reinterpret_cast<const bf16x8*>(&Vt[(dt * 16 + cl) * 72 + kc * 32 + g * 8]);
        oacc[dt] = __builtin_amdgcn_mfma_f32_16x16x32_bf16(pa, vbf, oacc[dt], 0, 0, 0);
      }
    }
    __syncthreads();
  }

  // normalize + store y (N,L,768) bf16
#pragma unroll
  for (int r = 0; r < 4; ++r) {
    int qr = qbase + wid * 16 + g * 4 + r;
    if (qr < LSEQ) {
      float inv = 1.f / lrow[r];
#pragma unroll
      for (int dt = 0; dt < 4; ++dt)
        y[((size_t)nb * LSEQ + qr) * CD + h * HD + dt * 16 + cl] = f2bf(oacc[dt][r] * inv);
    }
  }
}

// ---------------- K3: depthwise 3x3 conv on v patch tokens, add into y ------
__global__ __launch_bounds__(256) void dwc_add(
    const u16* __restrict__ v, const float* __restrict__ wd,
    const float* __restrict__ bd, u16* __restrict__ y) {
  int t = blockIdx.x * 256 + threadIdx.x;
  if (t >= NB * NH * 24 * 24 * 16) return;
  int d4 = t & 15; int tmp = t >> 4;
  int px = tmp % 24; tmp /= 24;
  int py = tmp % 24; tmp /= 24;
  int h = tmp % 12; int nb = tmp / 12;
  int c0 = h * 64 + d4 * 4;
  float acc[4];
#pragma unroll
  for (int j = 0; j < 4; ++j) acc[j] = bd[c0 + j];
  const u16* vh = v + ((size_t)nb * NH + h) * LSEQ * HD;
#pragma unroll
  for (int ky = 0; ky < 3; ++ky) {
    int y2 = py + ky - 1;
    if (y2 < 0 || y2 >= 24) continue;
#pragma unroll
    for (int kx = 0; kx < 3; ++kx) {
      int x2 = px + kx - 1;
      if (x2 < 0 || x2 >= 24) continue;
      int l = 1 + y2 * 24 + x2;
      ushort4 vv = *reinterpret_cast<const ushort4*>(&vh[l * HD + d4 * 4]);
      const u16* vp = (const u16*)&vv;
#pragma unroll
      for (int j = 0; j < 4; ++j)
        acc[j] += wd[(c0 + j) * 9 + ky * 3 + kx] * bf2f(vp[j]);
    }
  }
  size_t yi = ((size_t)nb * LSEQ + 1 + py * 24 + px) * CD + c0;
  ushort4 cur = *reinterpret_cast<ushort4*>(&y[yi]);
  u16* cp = (u16*)&cur;
#pragma unroll
  for (int j = 0; j < 4; ++j) cp[j] = f2bf(bf2f(cp[j]) + acc[j]);
  *reinterpret_cast<ushort4*>(&y[yi]) = cur;
}

// ---------------- K4: proj GEMM (M=18464, N=768, K=768) + bias, fp32 out ----
__global__ __launch_bounds__(256) void proj_gemm(
    const u16* __restrict__ yb, const float* __restrict__ wp,
    const float* __restrict__ bias, float* __restrict__ out) {
  __shared__ __align__(16) u16 As[128 * 40];
  __shared__ __align__(16) u16 Bs[128 * 40];
  const int m0 = blockIdx.x * 128;
  const int n0 = blockIdx.y * 128;
  const int t = threadIdx.x;
  const int lane = t & 63, wid = t >> 6;
  const int wm = wid >> 1, wn = wid & 1;
  const int g = lane >> 4, cl = lane & 15;
  const f32x4 fz = {0.f, 0.f, 0.f, 0.f};

  f32x4 acc[4][4];
#pragma unroll
  for (int i = 0; i < 4; ++i)
#pragma unroll
    for (int j = 0; j < 4; ++j) acc[i][j] = fz;

  for (int k0 = 0; k0 < CD; k0 += 32) {
#pragma unroll
    for (int i = 0; i < 2; ++i) {       // A: bf16, 128 rows x 4 chunks of 8 = 512 chunks
      int cidx = t + 256 * i;
      int row = cidx >> 2, d8 = (cidx & 3) << 3;   // FIXED: 32-elem rows (was >>3 / &7)
      int gr = m0 + row; gr = gr < MROWS ? gr : MROWS - 1;
      uint4 av = *reinterpret_cast<const uint4*>(yb + (size_t)gr * CD + k0 + d8);
      *reinterpret_cast<uint4*>(&As[row * 40 + d8]) = av;
    }
#pragma unroll
    for (int i = 0; i < 4; ++i) {       // B: fp32 -> bf16, 128 rows x 8 chunks of 4
      int f = t + 256 * i;
      int row = f >> 3, c4 = (f & 7) << 2;
      float4 bv = *reinterpret_cast<const float4*>(wp + (size_t)(n0 + row) * CD + k0 + c4);
      ushort4 bb;
      bb.x = f2bf(bv.x); bb.y = f2bf(bv.y); bb.z = f2bf(bv.z); bb.w = f2bf(bv.w);
      *reinterpret_cast<ushort4*>(&Bs[row * 40 + c4]) = bb;
    }
    __syncthreads();
    bf16x8 af[4], bfv[4];
#pragma unroll
    for (int mt = 0; mt < 4; ++mt)
      af[mt] = *reinterpret_cast<const bf16x8*>(&As[(wm * 64 + mt * 16 + cl) * 40 + g * 8]);
#pragma unroll
    for (int nt = 0; nt < 4; ++nt)
      bfv[nt] = *reinterpret_cast<const bf16x8*>(&Bs[(wn * 64 + nt * 16 + cl) * 40 + g * 8]);
#pragma unroll
    for (int mt = 0; mt < 4; ++mt)
#pragma unroll
      for (int nt = 0; nt < 4; ++nt)
        acc[mt][nt] = __builtin_amdgcn_mfma_f32_16x16x32_bf16(af[mt], bfv[nt], acc[mt][nt], 0, 0, 0);
    __syncthreads();
  }

#pragma unroll
  for (int nt = 0; nt < 4; ++nt) {
    int n = n0 + wn * 64 + nt * 16 + cl;
    float bn = bias[n];
#pragma unroll
    for (int mt = 0; mt < 4; ++mt)
#pragma unroll
      for (int r = 0; r < 4; ++r) {
        int m = m0 + wm * 64 + mt * 16 + g * 4 + r;
        if (m < MROWS) out[(size_t)m * CD + n] = acc[mt][nt][r] + bn;
      }
  }
}

extern "C" void kernel_launch(void* const* d_in, const int* in_sizes, int n_in,
                              void* d_out, int out_size, void* d_ws, size_t ws_size,
                              hipStream_t stream) {
  const float* x = (const float*)d_in[0];
  const float* w_qkv = (const float*)d_in[1];
  const float* w_proj = (const float*)d_in[2];
  const float* b_proj = (const float*)d_in[3];
  const float* w_dwc = (const float*)d_in[4];
  const float* b_dwc = (const float*)d_in[5];
  float* out = (float*)d_out;

  const size_t SEG = (size_t)NB * NH * LSEQ * HD;  // 14,180,352 elements
  u16* qb = (u16*)d_ws;
  u16* kb = qb + SEG;
  u16* vb = kb + SEG;
  u16* yb = vb + SEG;  // (N, L, 768) bf16

  qkv_gemm<<<dim3(145, 18), 256, 0, stream>>>(x, w_qkv, qb, kb, vb);
  attn_fwd<<<dim3(10, 12, 32), 256, 0, stream>>>(qb, kb, vb, yb);
  dwc_add<<<dim3((NB * NH * 24 * 24 * 16) / 256), 256, 0, stream>>>(vb, w_dwc, b_dwc, yb);
  proj_gemm<<<dim3(145, 6), 256, 0, stream>>>(yb, w_proj, b_proj, out);
}

// Round 3
// 479.824 us; speedup vs baseline: 1.1624x; 1.1624x over previous
//
#include <hip/hip_runtime.h>

typedef short bf16x8 __attribute__((ext_vector_type(8)));
typedef float f32x4 __attribute__((ext_vector_type(4)));
typedef unsigned short u16;

#define NB 32
#define LSEQ 577
#define CD 768
#define NH 12
#define HD 64
#define MROWS (NB * LSEQ)  // 18464
#define LPAD 584           // V^T row pad (multiple of 8 for aligned uint4)

__device__ __forceinline__ u16 f2bf(float f) {
  union { float f; unsigned u; } v; v.f = f;
  unsigned u = v.u + 0x7fffu + ((v.u >> 16) & 1u);  // RNE
  return (u16)(u >> 16);
}
__device__ __forceinline__ float bf2f(u16 s) {
  union { unsigned u; float f; } v; v.u = ((unsigned)s) << 16;
  return v.f;
}

// ---------------- K1: QKV GEMM  (M=18464, N=2304, K=768), NT layout ----------
// q,k scattered to (N,H,L,64) bf16; v scattered TRANSPOSED to (N,H,64,LPAD).
__global__ __launch_bounds__(256) void qkv_gemm(
    const float* __restrict__ x, const float* __restrict__ wq,
    u16* __restrict__ qb, u16* __restrict__ kb, u16* __restrict__ vtb) {
  __shared__ __align__(16) u16 As[128 * 40];
  __shared__ __align__(16) u16 Bs[128 * 40];
  const int m0 = blockIdx.x * 128;
  const int n0 = blockIdx.y * 128;
  const int t = threadIdx.x;
  const int lane = t & 63, wid = t >> 6;
  const int wm = wid >> 1, wn = wid & 1;
  const int g = lane >> 4, cl = lane & 15;
  const f32x4 fz = {0.f, 0.f, 0.f, 0.f};

  f32x4 acc[4][4];
#pragma unroll
  for (int i = 0; i < 4; ++i)
#pragma unroll
    for (int j = 0; j < 4; ++j) acc[i][j] = fz;

  for (int k0 = 0; k0 < CD; k0 += 32) {
#pragma unroll
    for (int i = 0; i < 4; ++i) {
      int f = t + 256 * i;            // 128 rows x 8 float4 chunks
      int row = f >> 3;
      int c4 = (f & 7) << 2;
      int gr = m0 + row; gr = gr < MROWS ? gr : MROWS - 1;
      float4 av = *reinterpret_cast<const float4*>(x + (size_t)gr * CD + k0 + c4);
      ushort4 ab;
      ab.x = f2bf(av.x); ab.y = f2bf(av.y); ab.z = f2bf(av.z); ab.w = f2bf(av.w);
      *reinterpret_cast<ushort4*>(&As[row * 40 + c4]) = ab;
      float4 bv = *reinterpret_cast<const float4*>(wq + (size_t)(n0 + row) * CD + k0 + c4);
      ushort4 bb;
      bb.x = f2bf(bv.x); bb.y = f2bf(bv.y); bb.z = f2bf(bv.z); bb.w = f2bf(bv.w);
      *reinterpret_cast<ushort4*>(&Bs[row * 40 + c4]) = bb;
    }
    __syncthreads();
    bf16x8 af[4], bfv[4];
#pragma unroll
    for (int mt = 0; mt < 4; ++mt)
      af[mt] = *reinterpret_cast<const bf16x8*>(&As[(wm * 64 + mt * 16 + cl) * 40 + g * 8]);
#pragma unroll
    for (int nt = 0; nt < 4; ++nt)
      bfv[nt] = *reinterpret_cast<const bf16x8*>(&Bs[(wn * 64 + nt * 16 + cl) * 40 + g * 8]);
#pragma unroll
    for (int mt = 0; mt < 4; ++mt)
#pragma unroll
      for (int nt = 0; nt < 4; ++nt)
        acc[mt][nt] = __builtin_amdgcn_mfma_f32_16x16x32_bf16(af[mt], bfv[nt], acc[mt][nt], 0, 0, 0);
    __syncthreads();
  }

  const int which = n0 / CD;          // uniform per block: 0=q, 1=k, 2=v
  const int rem0 = n0 % CD;
#pragma unroll
  for (int mt = 0; mt < 4; ++mt) {
#pragma unroll
    for (int nt = 0; nt < 4; ++nt) {
      int n = rem0 + wn * 64 + nt * 16 + cl;
      int hh = n >> 6, d = n & 63;
#pragma unroll
      for (int r = 0; r < 4; ++r) {
        int m = m0 + wm * 64 + mt * 16 + g * 4 + r;
        if (m < MROWS) {
          int nb = m / LSEQ, l = m % LSEQ;
          if (which == 0)
            qb[(((size_t)nb * NH + hh) * LSEQ + l) * HD + d] = f2bf(acc[mt][nt][r] * 0.125f);
          else if (which == 1)
            kb[(((size_t)nb * NH + hh) * LSEQ + l) * HD + d] = f2bf(acc[mt][nt][r]);
          else
            vtb[(((size_t)nb * NH + hh) * HD + d) * LPAD + l] = f2bf(acc[mt][nt][r]);
        }
      }
    }
  }
}

// ---------------- K2: flash attention (swapped-operand S^T / O^T form) ------
// block = (qtile, head, batch); 4 waves x 16 q-rows (q = lane&15 per lane).
__global__ __launch_bounds__(256) void attn_fwd(
    const u16* __restrict__ q, const u16* __restrict__ k,
    const u16* __restrict__ vt, u16* __restrict__ y) {
  __shared__ __align__(16) u16 Ks[64 * 72];       // [kk][d]
  __shared__ __align__(16) u16 Vts[64 * 72];      // [d][kk]  (from global V^T)
  __shared__ __align__(16) u16 Ps[4][16 * 72];    // per-wave P [q][kk]

  const int qtile = blockIdx.x;
  const int h = blockIdx.y;
  const int nb = blockIdx.z;
  const int t = threadIdx.x;
  const int lane = t & 63, wid = t >> 6;
  const int g = lane >> 4, cl = lane & 15;

  const size_t hoff = ((size_t)nb * NH + h) * LSEQ * HD;
  const u16* qh = q + hoff;
  const u16* kh = k + hoff;
  const u16* vth = vt + ((size_t)nb * NH + h) * HD * LPAD;

  const int qbase = qtile * 64;
  const int qrow = qbase + wid * 16 + cl;       // this lane's q-row
  const int qrc = qrow < LSEQ ? qrow : LSEQ - 1;
  // Q as B-operand: lane (cl,g) holds Q[q=cl][d=g*8..+7] (+32 for second half)
  bf16x8 qf0 = *reinterpret_cast<const bf16x8*>(qh + (size_t)qrc * HD + g * 8);
  bf16x8 qf1 = *reinterpret_cast<const bf16x8*>(qh + (size_t)qrc * HD + 32 + g * 8);

  const f32x4 fz = {0.f, 0.f, 0.f, 0.f};
  float mrow = -3.0e38f, lrow = 0.f;            // per-lane (q = cl)
  f32x4 oaccT[4];                               // O^T: row d=dt*16+g*4+r, col q=cl
#pragma unroll
  for (int dt = 0; dt < 4; ++dt) oaccT[dt] = fz;

  for (int kv = 0; kv < LSEQ; kv += 64) {
    // stage K rows [kk][d] and V^T rows [d][kk] (both row-major, vector ops)
#pragma unroll
    for (int i = 0; i < 2; ++i) {
      int cidx = t + 256 * i;                   // 64 rows x 8 chunks
      int row = cidx >> 3, c8 = (cidx & 7) << 3;
      int grow = kv + row;
      uint4 kd = {0, 0, 0, 0};
      if (grow < LSEQ) kd = *reinterpret_cast<const uint4*>(kh + (size_t)grow * HD + c8);
      *reinterpret_cast<uint4*>(&Ks[row * 72 + c8]) = kd;
      // V^T row d=row, cols kv+c8..+7; padded global rows -> always aligned.
      // Garbage beyond LSEQ is finite and multiplied by P=0.
      uint4 vd = *reinterpret_cast<const uint4*>(vth + (size_t)row * LPAD + kv + c8);
      *reinterpret_cast<uint4*>(&Vts[row * 72 + c8]) = vd;
    }
    __syncthreads();

    // S^T = K Q^T : lane (cl,g) gets S^T[kk = nt*16+g*4+r][q = cl]
    f32x4 sT[4];
#pragma unroll
    for (int nt = 0; nt < 4; ++nt) {
      bf16x8 a0 = *reinterpret_cast<const bf16x8*>(&Ks[(nt * 16 + cl) * 72 + g * 8]);
      bf16x8 a1 = *reinterpret_cast<const bf16x8*>(&Ks[(nt * 16 + cl) * 72 + 32 + g * 8]);
      f32x4 s = fz;
      s = __builtin_amdgcn_mfma_f32_16x16x32_bf16(a0, qf0, s, 0, 0, 0);
      s = __builtin_amdgcn_mfma_f32_16x16x32_bf16(a1, qf1, s, 0, 0, 0);
      sT[nt] = s;
    }

    // mask kk >= LSEQ
#pragma unroll
    for (int nt = 0; nt < 4; ++nt)
#pragma unroll
      for (int r = 0; r < 4; ++r)
        if (kv + nt * 16 + g * 4 + r >= LSEQ) sT[nt][r] = -3.0e38f;

    // online softmax, fully per-lane (q = cl): 16 regs + 2 shuffles
    float pm = -3.0e38f;
#pragma unroll
    for (int nt = 0; nt < 4; ++nt)
#pragma unroll
      for (int r = 0; r < 4; ++r) pm = fmaxf(pm, sT[nt][r]);
    pm = fmaxf(pm, __shfl_xor(pm, 16));
    pm = fmaxf(pm, __shfl_xor(pm, 32));

    float nm = fmaxf(mrow, pm);
    float alpha = __expf(mrow - nm);
    mrow = nm;
    float ps = 0.f;
#pragma unroll
    for (int nt = 0; nt < 4; ++nt)
#pragma unroll
      for (int r = 0; r < 4; ++r) {
        float p = __expf(sT[nt][r] - nm);       // masked -> exactly 0
        sT[nt][r] = p;
        ps += p;
      }
    ps += __shfl_xor(ps, 16);
    ps += __shfl_xor(ps, 32);
    lrow = lrow * alpha + ps;
#pragma unroll
    for (int dt = 0; dt < 4; ++dt) oaccT[dt] *= alpha;

    // P -> per-wave LDS [q=cl][kk], 4 packed b64 stores (bank-uniform)
#pragma unroll
    for (int nt = 0; nt < 4; ++nt) {
      ushort4 p4;
      p4.x = f2bf(sT[nt][0]); p4.y = f2bf(sT[nt][1]);
      p4.z = f2bf(sT[nt][2]); p4.w = f2bf(sT[nt][3]);
      *reinterpret_cast<ushort4*>(&Ps[wid][cl * 72 + nt * 16 + g * 4]) = p4;
    }
    __syncthreads();

    // O^T += V^T P^T : A = V^T rows d, B = P (consumed as P^T)
#pragma unroll
    for (int kc = 0; kc < 2; ++kc) {
      bf16x8 pa = *reinterpret_cast<const bf16x8*>(&Ps[wid][cl * 72 + kc * 32 + g * 8]);
#pragma unroll
      for (int dt = 0; dt < 4; ++dt) {
        bf16x8 va = *reinterpret_cast<const bf16x8*>(&Vts[(dt * 16 + cl) * 72 + kc * 32 + g * 8]);
        oaccT[dt] = __builtin_amdgcn_mfma_f32_16x16x32_bf16(va, pa, oaccT[dt], 0, 0, 0);
      }
    }
    __syncthreads();  // protect Ks/Vts before next stage
  }

  // store: lane (cl,g) holds O^T[d=dt*16+g*4+r][q=cl] -> 4 contiguous d
  if (qrow < LSEQ) {
    float inv = 1.f / lrow;
#pragma unroll
    for (int dt = 0; dt < 4; ++dt) {
      ushort4 o4;
      o4.x = f2bf(oaccT[dt][0] * inv); o4.y = f2bf(oaccT[dt][1] * inv);
      o4.z = f2bf(oaccT[dt][2] * inv); o4.w = f2bf(oaccT[dt][3] * inv);
      *reinterpret_cast<ushort4*>(
          &y[((size_t)nb * LSEQ + qrow) * CD + h * HD + dt * 16 + g * 4]) = o4;
    }
  }
}

// ---------------- K3: depthwise 3x3 conv (reads V^T), add into y ------------
// block = (d-half, head, batch): 32 channel-planes staged in LDS.
__global__ __launch_bounds__(256) void dwc_add(
    const u16* __restrict__ vt, const float* __restrict__ wd,
    const float* __restrict__ bd, u16* __restrict__ y) {
  __shared__ u16 V[32 * 588];   // 588*2=1176B row: 8B-aligned rows, odd dword stride/2
  const int d0 = blockIdx.x * 32;
  const int h = blockIdx.y;
  const int nb = blockIdx.z;
  const int t = threadIdx.x;
  const u16* vrow = vt + (((size_t)nb * NH + h) * HD + d0) * LPAD;

  // stage 32 rows x 584 cols (73 uint4 chunks per row, all aligned)
  for (int c = t; c < 32 * 73; c += 256) {
    int row = c / 73;
    int k0 = (c - row * 73) * 8;
    uint4 vv = *reinterpret_cast<const uint4*>(vrow + (size_t)row * LPAD + k0);
    const u16* vp = (const u16*)&vv;
    *reinterpret_cast<ushort4*>(&V[row * 588 + k0]) = *(const ushort4*)vp;
    *reinterpret_cast<ushort4*>(&V[row * 588 + k0 + 4]) = *(const ushort4*)(vp + 4);
  }
  __syncthreads();

  const int d = t & 31;
  const int c = h * HD + d0 + d;
  float w9[9];
#pragma unroll
  for (int j = 0; j < 9; ++j) w9[j] = wd[c * 9 + j];
  const float bias = bd[c];
  const u16* Vd = &V[d * 588];

  for (int it = 0; it < 72; ++it) {
    int li = (t >> 5) + it * 8;          // 0..575
    int py = li / 24, px = li - py * 24;
    float acc = bias;
#pragma unroll
    for (int ky = 0; ky < 3; ++ky) {
      int yy = py + ky - 1;
      if (yy < 0 || yy >= 24) continue;
      int base = 1 + yy * 24;
#pragma unroll
      for (int kx = 0; kx < 3; ++kx) {
        int xx = px + kx - 1;
        if (xx < 0 || xx >= 24) continue;
        acc += w9[ky * 3 + kx] * bf2f(Vd[base + xx]);
      }
    }
    size_t yi = ((size_t)nb * LSEQ + 1 + li) * CD + c;
    y[yi] = f2bf(bf2f(y[yi]) + acc);
  }
}

// ---------------- K4: proj GEMM (M=18464, N=768, K=768) + bias, fp32 out ----
__global__ __launch_bounds__(256) void proj_gemm(
    const u16* __restrict__ yb, const float* __restrict__ wp,
    const float* __restrict__ bias, float* __restrict__ out) {
  __shared__ __align__(16) u16 As[128 * 40];
  __shared__ __align__(16) u16 Bs[128 * 40];
  const int m0 = blockIdx.x * 128;
  const int n0 = blockIdx.y * 128;
  const int t = threadIdx.x;
  const int lane = t & 63, wid = t >> 6;
  const int wm = wid >> 1, wn = wid & 1;
  const int g = lane >> 4, cl = lane & 15;
  const f32x4 fz = {0.f, 0.f, 0.f, 0.f};

  f32x4 acc[4][4];
#pragma unroll
  for (int i = 0; i < 4; ++i)
#pragma unroll
    for (int j = 0; j < 4; ++j) acc[i][j] = fz;

  for (int k0 = 0; k0 < CD; k0 += 32) {
#pragma unroll
    for (int i = 0; i < 2; ++i) {       // A: bf16, 128 rows x 4 chunks of 8
      int cidx = t + 256 * i;
      int row = cidx >> 2, d8 = (cidx & 3) << 3;
      int gr = m0 + row; gr = gr < MROWS ? gr : MROWS - 1;
      uint4 av = *reinterpret_cast<const uint4*>(yb + (size_t)gr * CD + k0 + d8);
      *reinterpret_cast<uint4*>(&As[row * 40 + d8]) = av;
    }
#pragma unroll
    for (int i = 0; i < 4; ++i) {       // B: fp32 -> bf16, 128 rows x 8 chunks of 4
      int f = t + 256 * i;
      int row = f >> 3, c4 = (f & 7) << 2;
      float4 bv = *reinterpret_cast<const float4*>(wp + (size_t)(n0 + row) * CD + k0 + c4);
      ushort4 bb;
      bb.x = f2bf(bv.x); bb.y = f2bf(bv.y); bb.z = f2bf(bv.z); bb.w = f2bf(bv.w);
      *reinterpret_cast<ushort4*>(&Bs[row * 40 + c4]) = bb;
    }
    __syncthreads();
    bf16x8 af[4], bfv[4];
#pragma unroll
    for (int mt = 0; mt < 4; ++mt)
      af[mt] = *reinterpret_cast<const bf16x8*>(&As[(wm * 64 + mt * 16 + cl) * 40 + g * 8]);
#pragma unroll
    for (int nt = 0; nt < 4; ++nt)
      bfv[nt] = *reinterpret_cast<const bf16x8*>(&Bs[(wn * 64 + nt * 16 + cl) * 40 + g * 8]);
#pragma unroll
    for (int mt = 0; mt < 4; ++mt)
#pragma unroll
      for (int nt = 0; nt < 4; ++nt)
        acc[mt][nt] = __builtin_amdgcn_mfma_f32_16x16x32_bf16(af[mt], bfv[nt], acc[mt][nt], 0, 0, 0);
    __syncthreads();
  }

#pragma unroll
  for (int nt = 0; nt < 4; ++nt) {
    int n = n0 + wn * 64 + nt * 16 + cl;
    float bn = bias[n];
#pragma unroll
    for (int mt = 0; mt < 4; ++mt)
#pragma unroll
      for (int r = 0; r < 4; ++r) {
        int m = m0 + wm * 64 + mt * 16 + g * 4 + r;
        if (m < MROWS) out[(size_t)m * CD + n] = acc[mt][nt][r] + bn;
      }
  }
}

extern "C" void kernel_launch(void* const* d_in, const int* in_sizes, int n_in,
                              void* d_out, int out_size, void* d_ws, size_t ws_size,
                              hipStream_t stream) {
  const float* x = (const float*)d_in[0];
  const float* w_qkv = (const float*)d_in[1];
  const float* w_proj = (const float*)d_in[2];
  const float* b_proj = (const float*)d_in[3];
  const float* w_dwc = (const float*)d_in[4];
  const float* b_dwc = (const float*)d_in[5];
  float* out = (float*)d_out;

  const size_t SEG = (size_t)NB * NH * LSEQ * HD;   // 14,180,352
  const size_t SEGT = (size_t)NB * NH * HD * LPAD;  // 14,352,384
  u16* qb = (u16*)d_ws;
  u16* kb = qb + SEG;
  u16* vtb = kb + SEG;
  u16* yb = vtb + SEGT;  // (N, L, 768) bf16  (also absorbs V^T tail over-reads)

  qkv_gemm<<<dim3(145, 18), 256, 0, stream>>>(x, w_qkv, qb, kb, vtb);
  attn_fwd<<<dim3(10, 12, 32), 256, 0, stream>>>(qb, kb, vtb, yb);
  dwc_add<<<dim3(2, 12, 32), 256, 0, stream>>>(vtb, w_dwc, b_dwc, yb);
  proj_gemm<<<dim3(145, 6), 256, 0, stream>>>(yb, w_proj, b_proj, out);
}

// Round 4
// 403.982 us; speedup vs baseline: 1.3807x; 1.1877x over previous
//
#include <hip/hip_runtime.h>

typedef short bf16x8 __attribute__((ext_vector_type(8)));
typedef float f32x4 __attribute__((ext_vector_type(4)));
typedef unsigned short u16;

#define NB 32
#define LSEQ 577
#define CD 768
#define NH 12
#define HD 64
#define MROWS (NB * LSEQ)  // 18464
#define LPAD 584           // V^T row pad (multiple of 8 for aligned uint4)

#define GLD16(g, l)                                                    \
  __builtin_amdgcn_global_load_lds(                                    \
      (const __attribute__((address_space(1))) void*)(g),              \
      (__attribute__((address_space(3))) void*)(l), 16, 0, 0)

__device__ __forceinline__ u16 f2bf(float f) {
  union { float f; unsigned u; } v; v.f = f;
  unsigned u = v.u + 0x7fffu + ((v.u >> 16) & 1u);  // RNE
  return (u16)(u >> 16);
}
__device__ __forceinline__ float bf2f(u16 s) {
  union { unsigned u; float f; } v; v.u = ((unsigned)s) << 16;
  return v.f;
}

// ---------------- K0: fp32 -> bf16 conversion (vectorized, memory-bound) ----
__global__ __launch_bounds__(256) void cvt_bf16(
    const float* __restrict__ src, u16* __restrict__ dst, int n4) {
  int i = blockIdx.x * 256 + threadIdx.x;
  if (i < n4) {
    float4 v = reinterpret_cast<const float4*>(src)[i];
    ushort4 o;
    o.x = f2bf(v.x); o.y = f2bf(v.y); o.z = f2bf(v.z); o.w = f2bf(v.w);
    reinterpret_cast<ushort4*>(dst)[i] = o;
  }
}

// ---------------- K1: QKV GEMM (M=18464, N=2304, K=768), bf16 NT, m97-style -
// q,k scattered to (N,H,L,64) bf16; v scattered TRANSPOSED to (N,H,64,LPAD).
__global__ __launch_bounds__(256) void qkv_gemm(
    const u16* __restrict__ xb, const u16* __restrict__ wqb,
    u16* __restrict__ qb, u16* __restrict__ kb, u16* __restrict__ vtb) {
  __shared__ __align__(16) u16 As[128 * 32];   // linear [128][32] (gload_lds)
  __shared__ __align__(16) u16 Bs[128 * 32];
  const int m0 = blockIdx.x * 128;
  const int n0 = blockIdx.y * 128;
  const int t = threadIdx.x;
  const int lane = t & 63, wid = t >> 6;
  const int wm = wid >> 1, wn = wid & 1;
  const int g = lane >> 4, cl = lane & 15;

  // staging geometry: wave w fills LDS rows [w*32, w*32+32) via 2 issues;
  // HW writes lane l at dst + l*16B -> row = base+ l/4, col8 = (l&3)*8.
  const int srow = wid * 32 + (lane >> 2);
  const int scol = (lane & 3) * 8;
  int ga0 = m0 + srow;      ga0 = ga0 < MROWS ? ga0 : MROWS - 1;
  int ga1 = m0 + srow + 16; ga1 = ga1 < MROWS ? ga1 : MROWS - 1;
  const u16* asrc0 = xb + (size_t)ga0 * CD + scol;
  const u16* asrc1 = xb + (size_t)ga1 * CD + scol;
  const u16* bsrc0 = wqb + (size_t)(n0 + srow) * CD + scol;
  const u16* bsrc1 = wqb + (size_t)(n0 + srow + 16) * CD + scol;
  u16* adst0 = &As[wid * 1024];        // wave-uniform LDS bases
  u16* adst1 = &As[wid * 1024 + 512];
  u16* bdst0 = &Bs[wid * 1024];
  u16* bdst1 = &Bs[wid * 1024 + 512];

  const f32x4 fz = {0.f, 0.f, 0.f, 0.f};
  f32x4 acc[4][4];
#pragma unroll
  for (int i = 0; i < 4; ++i)
#pragma unroll
    for (int j = 0; j < 4; ++j) acc[i][j] = fz;

  for (int k0 = 0; k0 < CD; k0 += 32) {
    GLD16(asrc0 + k0, adst0);
    GLD16(asrc1 + k0, adst1);
    GLD16(bsrc0 + k0, bdst0);
    GLD16(bsrc1 + k0, bdst1);
    __syncthreads();   // compiler emits vmcnt(0) before barrier
    bf16x8 af[4], bfv[4];
#pragma unroll
    for (int mt = 0; mt < 4; ++mt)
      af[mt] = *reinterpret_cast<const bf16x8*>(&As[(wm * 64 + mt * 16 + cl) * 32 + g * 8]);
#pragma unroll
    for (int nt = 0; nt < 4; ++nt)
      bfv[nt] = *reinterpret_cast<const bf16x8*>(&Bs[(wn * 64 + nt * 16 + cl) * 32 + g * 8]);
#pragma unroll
    for (int mt = 0; mt < 4; ++mt)
#pragma unroll
      for (int nt = 0; nt < 4; ++nt)
        acc[mt][nt] = __builtin_amdgcn_mfma_f32_16x16x32_bf16(af[mt], bfv[nt], acc[mt][nt], 0, 0, 0);
    __syncthreads();
  }

  const int which = n0 / CD;          // uniform per block: 0=q, 1=k, 2=v
  const int rem0 = n0 % CD;
#pragma unroll
  for (int mt = 0; mt < 4; ++mt) {
#pragma unroll
    for (int nt = 0; nt < 4; ++nt) {
      int n = rem0 + wn * 64 + nt * 16 + cl;
      int hh = n >> 6, d = n & 63;
#pragma unroll
      for (int r = 0; r < 4; ++r) {
        int m = m0 + wm * 64 + mt * 16 + g * 4 + r;
        if (m < MROWS) {
          int nb = m / LSEQ, l = m % LSEQ;
          if (which == 0)
            qb[(((size_t)nb * NH + hh) * LSEQ + l) * HD + d] = f2bf(acc[mt][nt][r] * 0.125f);
          else if (which == 1)
            kb[(((size_t)nb * NH + hh) * LSEQ + l) * HD + d] = f2bf(acc[mt][nt][r]);
          else
            vtb[(((size_t)nb * NH + hh) * HD + d) * LPAD + l] = f2bf(acc[mt][nt][r]);
        }
      }
    }
  }
}

// ---------------- K2: flash attention (swapped-operand S^T / O^T form) ------
// block = (qtile, head, batch); 4 waves x 16 q-rows (q = lane&15 per lane).
__global__ __launch_bounds__(256) void attn_fwd(
    const u16* __restrict__ q, const u16* __restrict__ k,
    const u16* __restrict__ vt, u16* __restrict__ y) {
  __shared__ __align__(16) u16 Ks[64 * 72];       // [kk][d]
  __shared__ __align__(16) u16 Vts[64 * 72];      // [d][kk]  (from global V^T)
  __shared__ __align__(16) u16 Ps[4][16 * 72];    // per-wave P [q][kk]

  const int qtile = blockIdx.x;
  const int h = blockIdx.y;
  const int nb = blockIdx.z;
  const int t = threadIdx.x;
  const int lane = t & 63, wid = t >> 6;
  const int g = lane >> 4, cl = lane & 15;

  const size_t hoff = ((size_t)nb * NH + h) * LSEQ * HD;
  const u16* qh = q + hoff;
  const u16* kh = k + hoff;
  const u16* vth = vt + ((size_t)nb * NH + h) * HD * LPAD;

  const int qbase = qtile * 64;
  const int qrow = qbase + wid * 16 + cl;       // this lane's q-row
  const int qrc = qrow < LSEQ ? qrow : LSEQ - 1;
  bf16x8 qf0 = *reinterpret_cast<const bf16x8*>(qh + (size_t)qrc * HD + g * 8);
  bf16x8 qf1 = *reinterpret_cast<const bf16x8*>(qh + (size_t)qrc * HD + 32 + g * 8);

  const f32x4 fz = {0.f, 0.f, 0.f, 0.f};
  float mrow = -3.0e38f, lrow = 0.f;            // per-lane (q = cl)
  f32x4 oaccT[4];                               // O^T: row d=dt*16+g*4+r, col q=cl
#pragma unroll
  for (int dt = 0; dt < 4; ++dt) oaccT[dt] = fz;

  for (int kv = 0; kv < LSEQ; kv += 64) {
#pragma unroll
    for (int i = 0; i < 2; ++i) {
      int cidx = t + 256 * i;                   // 64 rows x 8 chunks
      int row = cidx >> 3, c8 = (cidx & 7) << 3;
      int grow = kv + row;
      uint4 kd = {0, 0, 0, 0};
      if (grow < LSEQ) kd = *reinterpret_cast<const uint4*>(kh + (size_t)grow * HD + c8);
      *reinterpret_cast<uint4*>(&Ks[row * 72 + c8]) = kd;
      uint4 vd = *reinterpret_cast<const uint4*>(vth + (size_t)row * LPAD + kv + c8);
      *reinterpret_cast<uint4*>(&Vts[row * 72 + c8]) = vd;
    }
    __syncthreads();

    // S^T = K Q^T : lane (cl,g) gets S^T[kk = nt*16+g*4+r][q = cl]
    f32x4 sT[4];
#pragma unroll
    for (int nt = 0; nt < 4; ++nt) {
      bf16x8 a0 = *reinterpret_cast<const bf16x8*>(&Ks[(nt * 16 + cl) * 72 + g * 8]);
      bf16x8 a1 = *reinterpret_cast<const bf16x8*>(&Ks[(nt * 16 + cl) * 72 + 32 + g * 8]);
      f32x4 s = fz;
      s = __builtin_amdgcn_mfma_f32_16x16x32_bf16(a0, qf0, s, 0, 0, 0);
      s = __builtin_amdgcn_mfma_f32_16x16x32_bf16(a1, qf1, s, 0, 0, 0);
      sT[nt] = s;
    }

#pragma unroll
    for (int nt = 0; nt < 4; ++nt)
#pragma unroll
      for (int r = 0; r < 4; ++r)
        if (kv + nt * 16 + g * 4 + r >= LSEQ) sT[nt][r] = -3.0e38f;

    // online softmax, per-lane (q = cl): 16 regs + 2 shuffles
    float pm = -3.0e38f;
#pragma unroll
    for (int nt = 0; nt < 4; ++nt)
#pragma unroll
      for (int r = 0; r < 4; ++r) pm = fmaxf(pm, sT[nt][r]);
    pm = fmaxf(pm, __shfl_xor(pm, 16));
    pm = fmaxf(pm, __shfl_xor(pm, 32));

    float nm = fmaxf(mrow, pm);
    float alpha = __expf(mrow - nm);
    mrow = nm;
    float ps = 0.f;
#pragma unroll
    for (int nt = 0; nt < 4; ++nt)
#pragma unroll
      for (int r = 0; r < 4; ++r) {
        float p = __expf(sT[nt][r] - nm);
        sT[nt][r] = p;
        ps += p;
      }
    ps += __shfl_xor(ps, 16);
    ps += __shfl_xor(ps, 32);
    lrow = lrow * alpha + ps;
#pragma unroll
    for (int dt = 0; dt < 4; ++dt) oaccT[dt] *= alpha;

    // P -> per-wave LDS [q=cl][kk], 4 packed b64 stores (bank-uniform)
#pragma unroll
    for (int nt = 0; nt < 4; ++nt) {
      ushort4 p4;
      p4.x = f2bf(sT[nt][0]); p4.y = f2bf(sT[nt][1]);
      p4.z = f2bf(sT[nt][2]); p4.w = f2bf(sT[nt][3]);
      *reinterpret_cast<ushort4*>(&Ps[wid][cl * 72 + nt * 16 + g * 4]) = p4;
    }
    __syncthreads();

    // O^T += V^T P^T
#pragma unroll
    for (int kc = 0; kc < 2; ++kc) {
      bf16x8 pa = *reinterpret_cast<const bf16x8*>(&Ps[wid][cl * 72 + kc * 32 + g * 8]);
#pragma unroll
      for (int dt = 0; dt < 4; ++dt) {
        bf16x8 va = *reinterpret_cast<const bf16x8*>(&Vts[(dt * 16 + cl) * 72 + kc * 32 + g * 8]);
        oaccT[dt] = __builtin_amdgcn_mfma_f32_16x16x32_bf16(va, pa, oaccT[dt], 0, 0, 0);
      }
    }
    __syncthreads();
  }

  if (qrow < LSEQ) {
    float inv = 1.f / lrow;
#pragma unroll
    for (int dt = 0; dt < 4; ++dt) {
      ushort4 o4;
      o4.x = f2bf(oaccT[dt][0] * inv); o4.y = f2bf(oaccT[dt][1] * inv);
      o4.z = f2bf(oaccT[dt][2] * inv); o4.w = f2bf(oaccT[dt][3] * inv);
      *reinterpret_cast<ushort4*>(
          &y[((size_t)nb * LSEQ + qrow) * CD + h * HD + dt * 16 + g * 4]) = o4;
    }
  }
}

// ---------------- K3: depthwise 3x3 conv (reads V^T), add into y ------------
__global__ __launch_bounds__(256) void dwc_add(
    const u16* __restrict__ vt, const float* __restrict__ wd,
    const float* __restrict__ bd, u16* __restrict__ y) {
  __shared__ u16 V[32 * 588];
  const int d0 = blockIdx.x * 32;
  const int h = blockIdx.y;
  const int nb = blockIdx.z;
  const int t = threadIdx.x;
  const u16* vrow = vt + (((size_t)nb * NH + h) * HD + d0) * LPAD;

  for (int c = t; c < 32 * 73; c += 256) {
    int row = c / 73;
    int k0 = (c - row * 73) * 8;
    uint4 vv = *reinterpret_cast<const uint4*>(vrow + (size_t)row * LPAD + k0);
    const u16* vp = (const u16*)&vv;
    *reinterpret_cast<ushort4*>(&V[row * 588 + k0]) = *(const ushort4*)vp;
    *reinterpret_cast<ushort4*>(&V[row * 588 + k0 + 4]) = *(const ushort4*)(vp + 4);
  }
  __syncthreads();

  const int d = t & 31;
  const int c = h * HD + d0 + d;
  float w9[9];
#pragma unroll
  for (int j = 0; j < 9; ++j) w9[j] = wd[c * 9 + j];
  const float bias = bd[c];
  const u16* Vd = &V[d * 588];

  for (int it = 0; it < 72; ++it) {
    int li = (t >> 5) + it * 8;
    int py = li / 24, px = li - py * 24;
    float acc = bias;
#pragma unroll
    for (int ky = 0; ky < 3; ++ky) {
      int yy = py + ky - 1;
      if (yy < 0 || yy >= 24) continue;
      int base = 1 + yy * 24;
#pragma unroll
      for (int kx = 0; kx < 3; ++kx) {
        int xx = px + kx - 1;
        if (xx < 0 || xx >= 24) continue;
        acc += w9[ky * 3 + kx] * bf2f(Vd[base + xx]);
      }
    }
    size_t yi = ((size_t)nb * LSEQ + 1 + li) * CD + c;
    y[yi] = f2bf(bf2f(y[yi]) + acc);
  }
}

// ---------------- K4: proj GEMM (M=18464, N=768, K=768), m97-style ----------
__global__ __launch_bounds__(256) void proj_gemm(
    const u16* __restrict__ yb, const u16* __restrict__ wpb,
    const float* __restrict__ bias, float* __restrict__ out) {
  __shared__ __align__(16) u16 As[128 * 32];
  __shared__ __align__(16) u16 Bs[128 * 32];
  const int m0 = blockIdx.x * 128;
  const int n0 = blockIdx.y * 128;
  const int t = threadIdx.x;
  const int lane = t & 63, wid = t >> 6;
  const int wm = wid >> 1, wn = wid & 1;
  const int g = lane >> 4, cl = lane & 15;

  const int srow = wid * 32 + (lane >> 2);
  const int scol = (lane & 3) * 8;
  int ga0 = m0 + srow;      ga0 = ga0 < MROWS ? ga0 : MROWS - 1;
  int ga1 = m0 + srow + 16; ga1 = ga1 < MROWS ? ga1 : MROWS - 1;
  const u16* asrc0 = yb + (size_t)ga0 * CD + scol;
  const u16* asrc1 = yb + (size_t)ga1 * CD + scol;
  const u16* bsrc0 = wpb + (size_t)(n0 + srow) * CD + scol;
  const u16* bsrc1 = wpb + (size_t)(n0 + srow + 16) * CD + scol;
  u16* adst0 = &As[wid * 1024];
  u16* adst1 = &As[wid * 1024 + 512];
  u16* bdst0 = &Bs[wid * 1024];
  u16* bdst1 = &Bs[wid * 1024 + 512];

  const f32x4 fz = {0.f, 0.f, 0.f, 0.f};
  f32x4 acc[4][4];
#pragma unroll
  for (int i = 0; i < 4; ++i)
#pragma unroll
    for (int j = 0; j < 4; ++j) acc[i][j] = fz;

  for (int k0 = 0; k0 < CD; k0 += 32) {
    GLD16(asrc0 + k0, adst0);
    GLD16(asrc1 + k0, adst1);
    GLD16(bsrc0 + k0, bdst0);
    GLD16(bsrc1 + k0, bdst1);
    __syncthreads();
    bf16x8 af[4], bfv[4];
#pragma unroll
    for (int mt = 0; mt < 4; ++mt)
      af[mt] = *reinterpret_cast<const bf16x8*>(&As[(wm * 64 + mt * 16 + cl) * 32 + g * 8]);
#pragma unroll
    for (int nt = 0; nt < 4; ++nt)
      bfv[nt] = *reinterpret_cast<const bf16x8*>(&Bs[(wn * 64 + nt * 16 + cl) * 32 + g * 8]);
#pragma unroll
    for (int mt = 0; mt < 4; ++mt)
#pragma unroll
      for (int nt = 0; nt < 4; ++nt)
        acc[mt][nt] = __builtin_amdgcn_mfma_f32_16x16x32_bf16(af[mt], bfv[nt], acc[mt][nt], 0, 0, 0);
    __syncthreads();
  }

#pragma unroll
  for (int nt = 0; nt < 4; ++nt) {
    int n = n0 + wn * 64 + nt * 16 + cl;
    float bn = bias[n];
#pragma unroll
    for (int mt = 0; mt < 4; ++mt)
#pragma unroll
      for (int r = 0; r < 4; ++r) {
        int m = m0 + wm * 64 + mt * 16 + g * 4 + r;
        if (m < MROWS) out[(size_t)m * CD + n] = acc[mt][nt][r] + bn;
      }
  }
}

extern "C" void kernel_launch(void* const* d_in, const int* in_sizes, int n_in,
                              void* d_out, int out_size, void* d_ws, size_t ws_size,
                              hipStream_t stream) {
  const float* x = (const float*)d_in[0];
  const float* w_qkv = (const float*)d_in[1];
  const float* w_proj = (const float*)d_in[2];
  const float* b_proj = (const float*)d_in[3];
  const float* w_dwc = (const float*)d_in[4];
  const float* b_dwc = (const float*)d_in[5];
  float* out = (float*)d_out;

  const size_t SEG = (size_t)NB * NH * LSEQ * HD;   // 14,180,352
  const size_t SEGT = (size_t)NB * NH * HD * LPAD;  // 14,352,384
  const size_t YN = (size_t)MROWS * CD;             // 14,180,352
  u16* yb = (u16*)d_ws;          // aliases xb: x needed only by qkv (before y)
  u16* xb = yb;
  u16* qb = yb + YN;
  u16* kb = qb + SEG;
  u16* vtb = kb + SEG;
  u16* wqb = vtb + SEGT;
  u16* wpb = wqb + (size_t)3 * CD * CD;

  cvt_bf16<<<dim3((int)(YN / 4 / 256)), 256, 0, stream>>>(x, xb, (int)(YN / 4));
  cvt_bf16<<<dim3(3 * CD * CD / 4 / 256), 256, 0, stream>>>(w_qkv, wqb, 3 * CD * CD / 4);
  cvt_bf16<<<dim3(CD * CD / 4 / 256), 256, 0, stream>>>(w_proj, wpb, CD * CD / 4);
  qkv_gemm<<<dim3(145, 18), 256, 0, stream>>>(xb, wqb, qb, kb, vtb);
  attn_fwd<<<dim3(10, 12, 32), 256, 0, stream>>>(qb, kb, vtb, yb);
  dwc_add<<<dim3(2, 12, 32), 256, 0, stream>>>(vtb, w_dwc, b_dwc, yb);
  proj_gemm<<<dim3(145, 6), 256, 0, stream>>>(yb, wpb, b_proj, out);
}

// Round 5
// 397.329 us; speedup vs baseline: 1.4038x; 1.0167x over previous
//
#include <hip/hip_runtime.h>

typedef short bf16x8 __attribute__((ext_vector_type(8)));
typedef float f32x4 __attribute__((ext_vector_type(4)));
typedef unsigned short u16;

#define NB 32
#define LSEQ 577
#define CD 768
#define NH 12
#define HD 64
#define MROWS (NB * LSEQ)  // 18464
#define LPAD 584           // V^T row pad (multiple of 8 for aligned uint4)

#define GLD16(g, l)                                                    \
  __builtin_amdgcn_global_load_lds(                                    \
      (const __attribute__((address_space(1))) void*)(g),              \
      (__attribute__((address_space(3))) void*)(l), 16, 0, 0)

__device__ __forceinline__ u16 f2bf(float f) {
  union { float f; unsigned u; } v; v.f = f;
  unsigned u = v.u + 0x7fffu + ((v.u >> 16) & 1u);  // RNE
  return (u16)(u >> 16);
}
__device__ __forceinline__ float bf2f(u16 s) {
  union { unsigned u; float f; } v; v.u = ((unsigned)s) << 16;
  return v.f;
}

// ---------------- K0: fp32 -> bf16 conversion (vectorized, memory-bound) ----
__global__ __launch_bounds__(256) void cvt_bf16(
    const float* __restrict__ src, u16* __restrict__ dst, int n4) {
  int i = blockIdx.x * 256 + threadIdx.x;
  if (i < n4) {
    float4 v = reinterpret_cast<const float4*>(src)[i];
    ushort4 o;
    o.x = f2bf(v.x); o.y = f2bf(v.y); o.z = f2bf(v.z); o.w = f2bf(v.w);
    reinterpret_cast<ushort4*>(dst)[i] = o;
  }
}

// ---------------- K1: QKV GEMM (M=18464, N=2304, K=768), 256^2 2-phase ------
// 512 thr / 8 waves (2M x 4N); BK=32; double-buffered LDS; prefetch next tile
// before computing current (T3-minimum recipe). q,k -> (N,H,L,64); v -> V^T.
__global__ __launch_bounds__(512, 2) void qkv_gemm(
    const u16* __restrict__ xb, const u16* __restrict__ wqb,
    u16* __restrict__ qb, u16* __restrict__ kb, u16* __restrict__ vtb) {
  __shared__ __align__(16) u16 As[2][256 * 32];   // linear [256][32] per buf
  __shared__ __align__(16) u16 Bs[2][256 * 32];
  const int m0 = blockIdx.x * 256;
  const int n0 = blockIdx.y * 256;
  const int t = threadIdx.x;
  const int lane = t & 63, wid = t >> 6;          // 8 waves
  const int wm = wid >> 2, wn = wid & 3;          // 2 x 4 wave grid
  const int g = lane >> 4, cl = lane & 15;

  // staging: each gload_lds issue = 1KB = 16 rows of 32 bf16.
  // wave w, issue0 -> rows [w*16, +16); issue1 -> rows [128 + w*16, +16).
  const int r16 = lane >> 2;            // row within 16-row group
  const int scol = (lane & 3) * 8;      // 8-elem chunk within 32-col row
  const int ra0 = wid * 16 + r16;
  const int ra1 = 128 + wid * 16 + r16;
  int gm0 = m0 + ra0; gm0 = gm0 < MROWS ? gm0 : MROWS - 1;
  int gm1 = m0 + ra1; gm1 = gm1 < MROWS ? gm1 : MROWS - 1;
  const u16* ax0 = xb + (size_t)gm0 * CD + scol;
  const u16* ax1 = xb + (size_t)gm1 * CD + scol;
  const u16* bx0 = wqb + (size_t)(n0 + ra0) * CD + scol;
  const u16* bx1 = wqb + (size_t)(n0 + ra1) * CD + scol;

  const f32x4 fz = {0.f, 0.f, 0.f, 0.f};
  f32x4 acc[8][4];
#pragma unroll
  for (int i = 0; i < 8; ++i)
#pragma unroll
    for (int j = 0; j < 4; ++j) acc[i][j] = fz;

#define QSTAGE(b, kt)                                  \
  do {                                                 \
    int kc = (kt) * 32;                                \
    GLD16(ax0 + kc, &As[b][wid * 512]);                \
    GLD16(ax1 + kc, &As[b][(wid + 8) * 512]);          \
    GLD16(bx0 + kc, &Bs[b][wid * 512]);                \
    GLD16(bx1 + kc, &Bs[b][(wid + 8) * 512]);          \
  } while (0)

  QSTAGE(0, 0);
  __syncthreads();
  int cur = 0;
  for (int kt = 0; kt < 24; ++kt) {
    if (kt < 23) QSTAGE(cur ^ 1, kt + 1);    // prefetch hides under MFMA below
    bf16x8 af[8], bfv[4];
#pragma unroll
    for (int mt = 0; mt < 8; ++mt)
      af[mt] = *reinterpret_cast<const bf16x8*>(&As[cur][(wm * 128 + mt * 16 + cl) * 32 + g * 8]);
#pragma unroll
    for (int nt = 0; nt < 4; ++nt)
      bfv[nt] = *reinterpret_cast<const bf16x8*>(&Bs[cur][(wn * 64 + nt * 16 + cl) * 32 + g * 8]);
    __builtin_amdgcn_s_setprio(1);
#pragma unroll
    for (int mt = 0; mt < 8; ++mt)
#pragma unroll
      for (int nt = 0; nt < 4; ++nt)
        acc[mt][nt] = __builtin_amdgcn_mfma_f32_16x16x32_bf16(af[mt], bfv[nt], acc[mt][nt], 0, 0, 0);
    __builtin_amdgcn_s_setprio(0);
    __syncthreads();                         // drains vmcnt+lgkm once per tile
    cur ^= 1;
  }
#undef QSTAGE

  const int which = n0 / CD;          // uniform per block: 0=q, 1=k, 2=v
  const int rem0 = n0 % CD;
#pragma unroll
  for (int mt = 0; mt < 8; ++mt) {
#pragma unroll
    for (int nt = 0; nt < 4; ++nt) {
      int rem = rem0 + wn * 64 + nt * 16 + cl;
      int hh = rem >> 6, d = rem & 63;
#pragma unroll
      for (int r = 0; r < 4; ++r) {
        int m = m0 + wm * 128 + mt * 16 + g * 4 + r;
        if (m < MROWS) {
          int nb = m / LSEQ, l = m - nb * LSEQ;
          if (which == 0)
            qb[(((size_t)nb * NH + hh) * LSEQ + l) * HD + d] = f2bf(acc[mt][nt][r] * 0.125f);
          else if (which == 1)
            kb[(((size_t)nb * NH + hh) * LSEQ + l) * HD + d] = f2bf(acc[mt][nt][r]);
          else
            vtb[(((size_t)nb * NH + hh) * HD + d) * LPAD + l] = f2bf(acc[mt][nt][r]);
        }
      }
    }
  }
}

// ---------------- K2: flash attention (swapped-operand S^T / O^T form) ------
// block = (qtile, head, batch); 4 waves x 16 q-rows (q = lane&15 per lane).
__global__ __launch_bounds__(256) void attn_fwd(
    const u16* __restrict__ q, const u16* __restrict__ k,
    const u16* __restrict__ vt, u16* __restrict__ y) {
  __shared__ __align__(16) u16 Ks[64 * 72];       // [kk][d]
  __shared__ __align__(16) u16 Vts[64 * 72];      // [d][kk]  (from global V^T)
  __shared__ __align__(16) u16 Ps[4][16 * 72];    // per-wave P [q][kk]

  const int qtile = blockIdx.x;
  const int h = blockIdx.y;
  const int nb = blockIdx.z;
  const int t = threadIdx.x;
  const int lane = t & 63, wid = t >> 6;
  const int g = lane >> 4, cl = lane & 15;

  const size_t hoff = ((size_t)nb * NH + h) * LSEQ * HD;
  const u16* qh = q + hoff;
  const u16* kh = k + hoff;
  const u16* vth = vt + ((size_t)nb * NH + h) * HD * LPAD;

  const int qbase = qtile * 64;
  const int qrow = qbase + wid * 16 + cl;       // this lane's q-row
  const int qrc = qrow < LSEQ ? qrow : LSEQ - 1;
  bf16x8 qf0 = *reinterpret_cast<const bf16x8*>(qh + (size_t)qrc * HD + g * 8);
  bf16x8 qf1 = *reinterpret_cast<const bf16x8*>(qh + (size_t)qrc * HD + 32 + g * 8);

  const f32x4 fz = {0.f, 0.f, 0.f, 0.f};
  float mrow = -3.0e38f, lrow = 0.f;            // per-lane (q = cl)
  f32x4 oaccT[4];                               // O^T: row d=dt*16+g*4+r, col q=cl
#pragma unroll
  for (int dt = 0; dt < 4; ++dt) oaccT[dt] = fz;

  for (int kv = 0; kv < LSEQ; kv += 64) {
#pragma unroll
    for (int i = 0; i < 2; ++i) {
      int cidx = t + 256 * i;                   // 64 rows x 8 chunks
      int row = cidx >> 3, c8 = (cidx & 7) << 3;
      int grow = kv + row;
      uint4 kd = {0, 0, 0, 0};
      if (grow < LSEQ) kd = *reinterpret_cast<const uint4*>(kh + (size_t)grow * HD + c8);
      *reinterpret_cast<uint4*>(&Ks[row * 72 + c8]) = kd;
      uint4 vd = *reinterpret_cast<const uint4*>(vth + (size_t)row * LPAD + kv + c8);
      *reinterpret_cast<uint4*>(&Vts[row * 72 + c8]) = vd;
    }
    __syncthreads();

    // S^T = K Q^T : lane (cl,g) gets S^T[kk = nt*16+g*4+r][q = cl]
    f32x4 sT[4];
#pragma unroll
    for (int nt = 0; nt < 4; ++nt) {
      bf16x8 a0 = *reinterpret_cast<const bf16x8*>(&Ks[(nt * 16 + cl) * 72 + g * 8]);
      bf16x8 a1 = *reinterpret_cast<const bf16x8*>(&Ks[(nt * 16 + cl) * 72 + 32 + g * 8]);
      f32x4 s = fz;
      s = __builtin_amdgcn_mfma_f32_16x16x32_bf16(a0, qf0, s, 0, 0, 0);
      s = __builtin_amdgcn_mfma_f32_16x16x32_bf16(a1, qf1, s, 0, 0, 0);
      sT[nt] = s;
    }

#pragma unroll
    for (int nt = 0; nt < 4; ++nt)
#pragma unroll
      for (int r = 0; r < 4; ++r)
        if (kv + nt * 16 + g * 4 + r >= LSEQ) sT[nt][r] = -3.0e38f;

    // online softmax, per-lane (q = cl): 16 regs + 2 shuffles
    float pm = -3.0e38f;
#pragma unroll
    for (int nt = 0; nt < 4; ++nt)
#pragma unroll
      for (int r = 0; r < 4; ++r) pm = fmaxf(pm, sT[nt][r]);
    pm = fmaxf(pm, __shfl_xor(pm, 16));
    pm = fmaxf(pm, __shfl_xor(pm, 32));

    float nm = fmaxf(mrow, pm);
    float alpha = __expf(mrow - nm);
    mrow = nm;
    float ps = 0.f;
#pragma unroll
    for (int nt = 0; nt < 4; ++nt)
#pragma unroll
      for (int r = 0; r < 4; ++r) {
        float p = __expf(sT[nt][r] - nm);
        sT[nt][r] = p;
        ps += p;
      }
    ps += __shfl_xor(ps, 16);
    ps += __shfl_xor(ps, 32);
    lrow = lrow * alpha + ps;
#pragma unroll
    for (int dt = 0; dt < 4; ++dt) oaccT[dt] *= alpha;

    // P -> per-wave LDS [q=cl][kk], 4 packed b64 stores (bank-uniform)
#pragma unroll
    for (int nt = 0; nt < 4; ++nt) {
      ushort4 p4;
      p4.x = f2bf(sT[nt][0]); p4.y = f2bf(sT[nt][1]);
      p4.z = f2bf(sT[nt][2]); p4.w = f2bf(sT[nt][3]);
      *reinterpret_cast<ushort4*>(&Ps[wid][cl * 72 + nt * 16 + g * 4]) = p4;
    }
    __syncthreads();

    // O^T += V^T P^T
#pragma unroll
    for (int kc = 0; kc < 2; ++kc) {
      bf16x8 pa = *reinterpret_cast<const bf16x8*>(&Ps[wid][cl * 72 + kc * 32 + g * 8]);
#pragma unroll
      for (int dt = 0; dt < 4; ++dt) {
        bf16x8 va = *reinterpret_cast<const bf16x8*>(&Vts[(dt * 16 + cl) * 72 + kc * 32 + g * 8]);
        oaccT[dt] = __builtin_amdgcn_mfma_f32_16x16x32_bf16(va, pa, oaccT[dt], 0, 0, 0);
      }
    }
    __syncthreads();
  }

  if (qrow < LSEQ) {
    float inv = 1.f / lrow;
#pragma unroll
    for (int dt = 0; dt < 4; ++dt) {
      ushort4 o4;
      o4.x = f2bf(oaccT[dt][0] * inv); o4.y = f2bf(oaccT[dt][1] * inv);
      o4.z = f2bf(oaccT[dt][2] * inv); o4.w = f2bf(oaccT[dt][3] * inv);
      *reinterpret_cast<ushort4*>(
          &y[((size_t)nb * LSEQ + qrow) * CD + h * HD + dt * 16 + g * 4]) = o4;
    }
  }
}

// ---------------- K3: depthwise 3x3 conv (reads V^T), add into y ------------
__global__ __launch_bounds__(256) void dwc_add(
    const u16* __restrict__ vt, const float* __restrict__ wd,
    const float* __restrict__ bd, u16* __restrict__ y) {
  __shared__ u16 V[32 * 588];
  const int d0 = blockIdx.x * 32;
  const int h = blockIdx.y;
  const int nb = blockIdx.z;
  const int t = threadIdx.x;
  const u16* vrow = vt + (((size_t)nb * NH + h) * HD + d0) * LPAD;

  for (int c = t; c < 32 * 73; c += 256) {
    int row = c / 73;
    int k0 = (c - row * 73) * 8;
    uint4 vv = *reinterpret_cast<const uint4*>(vrow + (size_t)row * LPAD + k0);
    const u16* vp = (const u16*)&vv;
    *reinterpret_cast<ushort4*>(&V[row * 588 + k0]) = *(const ushort4*)vp;
    *reinterpret_cast<ushort4*>(&V[row * 588 + k0 + 4]) = *(const ushort4*)(vp + 4);
  }
  __syncthreads();

  const int d = t & 31;
  const int c = h * HD + d0 + d;
  float w9[9];
#pragma unroll
  for (int j = 0; j < 9; ++j) w9[j] = wd[c * 9 + j];
  const float bias = bd[c];
  const u16* Vd = &V[d * 588];

  for (int it = 0; it < 72; ++it) {
    int li = (t >> 5) + it * 8;
    int py = li / 24, px = li - py * 24;
    float acc = bias;
#pragma unroll
    for (int ky = 0; ky < 3; ++ky) {
      int yy = py + ky - 1;
      if (yy < 0 || yy >= 24) continue;
      int base = 1 + yy * 24;
#pragma unroll
      for (int kx = 0; kx < 3; ++kx) {
        int xx = px + kx - 1;
        if (xx < 0 || xx >= 24) continue;
        acc += w9[ky * 3 + kx] * bf2f(Vd[base + xx]);
      }
    }
    size_t yi = ((size_t)nb * LSEQ + 1 + li) * CD + c;
    y[yi] = f2bf(bf2f(y[yi]) + acc);
  }
}

// ---------------- K4: proj GEMM (M=18464, N=768, K=768), 128^2 2-phase ------
__global__ __launch_bounds__(256) void proj_gemm(
    const u16* __restrict__ yb, const u16* __restrict__ wpb,
    const float* __restrict__ bias, float* __restrict__ out) {
  __shared__ __align__(16) u16 As[2][128 * 32];
  __shared__ __align__(16) u16 Bs[2][128 * 32];
  const int m0 = blockIdx.x * 128;
  const int n0 = blockIdx.y * 128;
  const int t = threadIdx.x;
  const int lane = t & 63, wid = t >> 6;
  const int wm = wid >> 1, wn = wid & 1;
  const int g = lane >> 4, cl = lane & 15;

  const int srow = wid * 32 + (lane >> 2);
  const int scol = (lane & 3) * 8;
  int ga0 = m0 + srow;      ga0 = ga0 < MROWS ? ga0 : MROWS - 1;
  int ga1 = m0 + srow + 16; ga1 = ga1 < MROWS ? ga1 : MROWS - 1;
  const u16* asrc0 = yb + (size_t)ga0 * CD + scol;
  const u16* asrc1 = yb + (size_t)ga1 * CD + scol;
  const u16* bsrc0 = wpb + (size_t)(n0 + srow) * CD + scol;
  const u16* bsrc1 = wpb + (size_t)(n0 + srow + 16) * CD + scol;

  const f32x4 fz = {0.f, 0.f, 0.f, 0.f};
  f32x4 acc[4][4];
#pragma unroll
  for (int i = 0; i < 4; ++i)
#pragma unroll
    for (int j = 0; j < 4; ++j) acc[i][j] = fz;

#define PSTAGE(b, kt)                                   \
  do {                                                  \
    int kc = (kt) * 32;                                 \
    GLD16(asrc0 + kc, &As[b][wid * 1024]);              \
    GLD16(asrc1 + kc, &As[b][wid * 1024 + 512]);        \
    GLD16(bsrc0 + kc, &Bs[b][wid * 1024]);              \
    GLD16(bsrc1 + kc, &Bs[b][wid * 1024 + 512]);        \
  } while (0)

  PSTAGE(0, 0);
  __syncthreads();
  int cur = 0;
  for (int kt = 0; kt < 24; ++kt) {
    if (kt < 23) PSTAGE(cur ^ 1, kt + 1);
    bf16x8 af[4], bfv[4];
#pragma unroll
    for (int mt = 0; mt < 4; ++mt)
      af[mt] = *reinterpret_cast<const bf16x8*>(&As[cur][(wm * 64 + mt * 16 + cl) * 32 + g * 8]);
#pragma unroll
    for (int nt = 0; nt < 4; ++nt)
      bfv[nt] = *reinterpret_cast<const bf16x8*>(&Bs[cur][(wn * 64 + nt * 16 + cl) * 32 + g * 8]);
    __builtin_amdgcn_s_setprio(1);
#pragma unroll
    for (int mt = 0; mt < 4; ++mt)
#pragma unroll
      for (int nt = 0; nt < 4; ++nt)
        acc[mt][nt] = __builtin_amdgcn_mfma_f32_16x16x32_bf16(af[mt], bfv[nt], acc[mt][nt], 0, 0, 0);
    __builtin_amdgcn_s_setprio(0);
    __syncthreads();
    cur ^= 1;
  }
#undef PSTAGE

#pragma unroll
  for (int nt = 0; nt < 4; ++nt) {
    int n = n0 + wn * 64 + nt * 16 + cl;
    float bn = bias[n];
#pragma unroll
    for (int mt = 0; mt < 4; ++mt)
#pragma unroll
      for (int r = 0; r < 4; ++r) {
        int m = m0 + wm * 64 + mt * 16 + g * 4 + r;
        if (m < MROWS) out[(size_t)m * CD + n] = acc[mt][nt][r] + bn;
      }
  }
}

extern "C" void kernel_launch(void* const* d_in, const int* in_sizes, int n_in,
                              void* d_out, int out_size, void* d_ws, size_t ws_size,
                              hipStream_t stream) {
  const float* x = (const float*)d_in[0];
  const float* w_qkv = (const float*)d_in[1];
  const float* w_proj = (const float*)d_in[2];
  const float* b_proj = (const float*)d_in[3];
  const float* w_dwc = (const float*)d_in[4];
  const float* b_dwc = (const float*)d_in[5];
  float* out = (float*)d_out;

  const size_t SEG = (size_t)NB * NH * LSEQ * HD;   // 14,180,352
  const size_t SEGT = (size_t)NB * NH * HD * LPAD;  // 14,352,384
  const size_t YN = (size_t)MROWS * CD;             // 14,180,352
  u16* yb = (u16*)d_ws;          // aliases xb: x needed only by qkv (before y)
  u16* xb = yb;
  u16* qb = yb + YN;
  u16* kb = qb + SEG;
  u16* vtb = kb + SEG;
  u16* wqb = vtb + SEGT;
  u16* wpb = wqb + (size_t)3 * CD * CD;

  cvt_bf16<<<dim3((int)(YN / 4 / 256)), 256, 0, stream>>>(x, xb, (int)(YN / 4));
  cvt_bf16<<<dim3(3 * CD * CD / 4 / 256), 256, 0, stream>>>(w_qkv, wqb, 3 * CD * CD / 4);
  cvt_bf16<<<dim3(CD * CD / 4 / 256), 256, 0, stream>>>(w_proj, wpb, CD * CD / 4);
  qkv_gemm<<<dim3(73, 9), 512, 0, stream>>>(xb, wqb, qb, kb, vtb);
  attn_fwd<<<dim3(10, 12, 32), 256, 0, stream>>>(qb, kb, vtb, yb);
  dwc_add<<<dim3(2, 12, 32), 256, 0, stream>>>(vtb, w_dwc, b_dwc, yb);
  proj_gemm<<<dim3(145, 6), 256, 0, stream>>>(yb, wpb, b_proj, out);
}

// Round 6
// 394.355 us; speedup vs baseline: 1.4144x; 1.0075x over previous
//
#include <hip/hip_runtime.h>

typedef short bf16x8 __attribute__((ext_vector_type(8)));
typedef float f32x4 __attribute__((ext_vector_type(4)));
typedef unsigned short u16;

#define NB 32
#define LSEQ 577
#define CD 768
#define NH 12
#define HD 64
#define MROWS (NB * LSEQ)  // 18464
#define LPAD 584           // V^T row pad (multiple of 8 for aligned uint4)

#define GLD16(g, l)                                                    \
  __builtin_amdgcn_global_load_lds(                                    \
      (const __attribute__((address_space(1))) void*)(g),              \
      (__attribute__((address_space(3))) void*)(l), 16, 0, 0)

__device__ __forceinline__ u16 f2bf(float f) {
  union { float f; unsigned u; } v; v.f = f;
  unsigned u = v.u + 0x7fffu + ((v.u >> 16) & 1u);  // RNE
  return (u16)(u >> 16);
}
__device__ __forceinline__ float bf2f(u16 s) {
  union { unsigned u; float f; } v; v.u = ((unsigned)s) << 16;
  return v.f;
}

// ---------------- K0: fp32 -> bf16 conversion (vectorized, memory-bound) ----
__global__ __launch_bounds__(256) void cvt_bf16(
    const float* __restrict__ src, u16* __restrict__ dst, int n4) {
  int i = blockIdx.x * 256 + threadIdx.x;
  if (i < n4) {
    float4 v = reinterpret_cast<const float4*>(src)[i];
    ushort4 o;
    o.x = f2bf(v.x); o.y = f2bf(v.y); o.z = f2bf(v.z); o.w = f2bf(v.w);
    reinterpret_cast<ushort4*>(dst)[i] = o;
  }
}

// ---------------- K1: QKV GEMM (M=18464, N=2304, K=768) ---------------------
// 256^2 tile, BK=32, 8 waves (2Mx4N). 3-buffer circular LDS, depth-2 prefetch,
// counted vmcnt(4) + raw s_barrier: loads stay in flight across barriers (T4).
__global__ __launch_bounds__(512, 2) void qkv_gemm(
    const u16* __restrict__ xb, const u16* __restrict__ wqb,
    u16* __restrict__ qb, u16* __restrict__ kb, u16* __restrict__ vtb) {
  __shared__ __align__(16) u16 As[3][256 * 32];   // 3 x 16 KB
  __shared__ __align__(16) u16 Bs[3][256 * 32];   // 3 x 16 KB (total 96 KB)
  const int m0 = blockIdx.x * 256;
  const int n0 = blockIdx.y * 256;
  const int t = threadIdx.x;
  const int lane = t & 63, wid = t >> 6;          // 8 waves
  const int wm = wid >> 2, wn = wid & 3;          // 2 x 4 wave grid
  const int g = lane >> 4, cl = lane & 15;

  // staging: wave w issue0 -> rows [w*16,+16); issue1 -> rows [128+w*16,+16)
  const int r16 = lane >> 2;
  const int scol = (lane & 3) * 8;
  const int ra0 = wid * 16 + r16;
  const int ra1 = 128 + wid * 16 + r16;
  int gm0 = m0 + ra0; gm0 = gm0 < MROWS ? gm0 : MROWS - 1;
  int gm1 = m0 + ra1; gm1 = gm1 < MROWS ? gm1 : MROWS - 1;
  const u16* ax0 = xb + (size_t)gm0 * CD + scol;
  const u16* ax1 = xb + (size_t)gm1 * CD + scol;
  const u16* bx0 = wqb + (size_t)(n0 + ra0) * CD + scol;
  const u16* bx1 = wqb + (size_t)(n0 + ra1) * CD + scol;

  const f32x4 fz = {0.f, 0.f, 0.f, 0.f};
  f32x4 acc[8][4];
#pragma unroll
  for (int i = 0; i < 8; ++i)
#pragma unroll
    for (int j = 0; j < 4; ++j) acc[i][j] = fz;

#define QSTAGE(b, kt)                                  \
  do {                                                 \
    int kc = (kt) * 32;                                \
    GLD16(ax0 + kc, &As[b][wid * 512]);                \
    GLD16(ax1 + kc, &As[b][(wid + 8) * 512]);          \
    GLD16(bx0 + kc, &Bs[b][wid * 512]);                \
    GLD16(bx1 + kc, &Bs[b][(wid + 8) * 512]);          \
  } while (0)

  QSTAGE(0, 0);
  QSTAGE(1, 1);
  // K-loop: 24 steps. Invariant at top of step kt: in-flight = stage(kt) +
  // stage(kt+1) (8 loads). vmcnt(4) completes stage(kt); barrier publishes all
  // waves' stage(kt) LDS writes AND proves compute(kt-1) done, so issuing
  // stage(kt+2) into buf (kt+2)%3 == (kt-1)%3 is safe.
  for (int kt = 0; kt < 24; ++kt) {
    const int cb = kt % 3;
    if (kt < 23) asm volatile("s_waitcnt vmcnt(4)" ::: "memory");
    else         asm volatile("s_waitcnt vmcnt(0)" ::: "memory");
    __builtin_amdgcn_s_barrier();
    if (kt < 22) QSTAGE((kt + 2) % 3, kt + 2);
    bf16x8 af[8], bfv[4];
#pragma unroll
    for (int mt = 0; mt < 8; ++mt)
      af[mt] = *reinterpret_cast<const bf16x8*>(&As[cb][(wm * 128 + mt * 16 + cl) * 32 + g * 8]);
#pragma unroll
    for (int nt = 0; nt < 4; ++nt)
      bfv[nt] = *reinterpret_cast<const bf16x8*>(&Bs[cb][(wn * 64 + nt * 16 + cl) * 32 + g * 8]);
    __builtin_amdgcn_s_setprio(1);
#pragma unroll
    for (int mt = 0; mt < 8; ++mt)
#pragma unroll
      for (int nt = 0; nt < 4; ++nt)
        acc[mt][nt] = __builtin_amdgcn_mfma_f32_16x16x32_bf16(af[mt], bfv[nt], acc[mt][nt], 0, 0, 0);
    __builtin_amdgcn_s_setprio(0);
  }
#undef QSTAGE

  const int which = n0 / CD;          // uniform per block: 0=q, 1=k, 2=v
  const int rem0 = n0 % CD;
#pragma unroll
  for (int mt = 0; mt < 8; ++mt) {
#pragma unroll
    for (int nt = 0; nt < 4; ++nt) {
      int rem = rem0 + wn * 64 + nt * 16 + cl;
      int hh = rem >> 6, d = rem & 63;
#pragma unroll
      for (int r = 0; r < 4; ++r) {
        int m = m0 + wm * 128 + mt * 16 + g * 4 + r;
        if (m < MROWS) {
          int nb = m / LSEQ, l = m - nb * LSEQ;
          if (which == 0)
            qb[(((size_t)nb * NH + hh) * LSEQ + l) * HD + d] = f2bf(acc[mt][nt][r] * 0.125f);
          else if (which == 1)
            kb[(((size_t)nb * NH + hh) * LSEQ + l) * HD + d] = f2bf(acc[mt][nt][r]);
          else
            vtb[(((size_t)nb * NH + hh) * HD + d) * LPAD + l] = f2bf(acc[mt][nt][r]);
        }
      }
    }
  }
}

// ---------------- K2: flash attention (swapped-operand S^T / O^T form) ------
// block = (qtile of 128 rows, head, batch); 8 waves x 16 q-rows.
__global__ __launch_bounds__(512) void attn_fwd(
    const u16* __restrict__ q, const u16* __restrict__ k,
    const u16* __restrict__ vt, u16* __restrict__ y) {
  __shared__ __align__(16) u16 Ks[64 * 72];       // [kk][d]
  __shared__ __align__(16) u16 Vts[64 * 72];      // [d][kk]  (from global V^T)
  __shared__ __align__(16) u16 Ps[8][16 * 72];    // per-wave P [q][kk]

  const int qtile = blockIdx.x;
  const int h = blockIdx.y;
  const int nb = blockIdx.z;
  const int t = threadIdx.x;
  const int lane = t & 63, wid = t >> 6;          // 8 waves
  const int g = lane >> 4, cl = lane & 15;

  const size_t hoff = ((size_t)nb * NH + h) * LSEQ * HD;
  const u16* qh = q + hoff;
  const u16* kh = k + hoff;
  const u16* vth = vt + ((size_t)nb * NH + h) * HD * LPAD;

  const int qbase = qtile * 128;
  const int qrow = qbase + wid * 16 + cl;       // this lane's q-row
  const int qrc = qrow < LSEQ ? qrow : LSEQ - 1;
  bf16x8 qf0 = *reinterpret_cast<const bf16x8*>(qh + (size_t)qrc * HD + g * 8);
  bf16x8 qf1 = *reinterpret_cast<const bf16x8*>(qh + (size_t)qrc * HD + 32 + g * 8);

  const f32x4 fz = {0.f, 0.f, 0.f, 0.f};
  float mrow = -3.0e38f, lrow = 0.f;            // per-lane (q = cl)
  f32x4 oaccT[4];                               // O^T: row d=dt*16+g*4+r, col q=cl
#pragma unroll
  for (int dt = 0; dt < 4; ++dt) oaccT[dt] = fz;

  for (int kv = 0; kv < LSEQ; kv += 64) {
    {
      int row = t >> 3, c8 = (t & 7) << 3;      // 512 chunks = 64 rows x 8
      int grow = kv + row;
      uint4 kd = {0, 0, 0, 0};
      if (grow < LSEQ) kd = *reinterpret_cast<const uint4*>(kh + (size_t)grow * HD + c8);
      *reinterpret_cast<uint4*>(&Ks[row * 72 + c8]) = kd;
      uint4 vd = *reinterpret_cast<const uint4*>(vth + (size_t)row * LPAD + kv + c8);
      *reinterpret_cast<uint4*>(&Vts[row * 72 + c8]) = vd;
    }
    __syncthreads();

    // S^T = K Q^T : lane (cl,g) gets S^T[kk = nt*16+g*4+r][q = cl]
    f32x4 sT[4];
#pragma unroll
    for (int nt = 0; nt < 4; ++nt) {
      bf16x8 a0 = *reinterpret_cast<const bf16x8*>(&Ks[(nt * 16 + cl) * 72 + g * 8]);
      bf16x8 a1 = *reinterpret_cast<const bf16x8*>(&Ks[(nt * 16 + cl) * 72 + 32 + g * 8]);
      f32x4 s = fz;
      s = __builtin_amdgcn_mfma_f32_16x16x32_bf16(a0, qf0, s, 0, 0, 0);
      s = __builtin_amdgcn_mfma_f32_16x16x32_bf16(a1, qf1, s, 0, 0, 0);
      sT[nt] = s;
    }

#pragma unroll
    for (int nt = 0; nt < 4; ++nt)
#pragma unroll
      for (int r = 0; r < 4; ++r)
        if (kv + nt * 16 + g * 4 + r >= LSEQ) sT[nt][r] = -3.0e38f;

    // online softmax, per-lane (q = cl): 16 regs + 2 shuffles
    float pm = -3.0e38f;
#pragma unroll
    for (int nt = 0; nt < 4; ++nt)
#pragma unroll
      for (int r = 0; r < 4; ++r) pm = fmaxf(pm, sT[nt][r]);
    pm = fmaxf(pm, __shfl_xor(pm, 16));
    pm = fmaxf(pm, __shfl_xor(pm, 32));

    float nm = fmaxf(mrow, pm);
    float alpha = __expf(mrow - nm);
    mrow = nm;
    float ps = 0.f;
#pragma unroll
    for (int nt = 0; nt < 4; ++nt)
#pragma unroll
      for (int r = 0; r < 4; ++r) {
        float p = __expf(sT[nt][r] - nm);
        sT[nt][r] = p;
        ps += p;
      }
    ps += __shfl_xor(ps, 16);
    ps += __shfl_xor(ps, 32);
    lrow = lrow * alpha + ps;
#pragma unroll
    for (int dt = 0; dt < 4; ++dt) oaccT[dt] *= alpha;

    // P -> per-wave LDS [q=cl][kk], 4 packed b64 stores (bank-uniform)
#pragma unroll
    for (int nt = 0; nt < 4; ++nt) {
      ushort4 p4;
      p4.x = f2bf(sT[nt][0]); p4.y = f2bf(sT[nt][1]);
      p4.z = f2bf(sT[nt][2]); p4.w = f2bf(sT[nt][3]);
      *reinterpret_cast<ushort4*>(&Ps[wid][cl * 72 + nt * 16 + g * 4]) = p4;
    }
    __syncthreads();

    // O^T += V^T P^T
#pragma unroll
    for (int kc = 0; kc < 2; ++kc) {
      bf16x8 pa = *reinterpret_cast<const bf16x8*>(&Ps[wid][cl * 72 + kc * 32 + g * 8]);
#pragma unroll
      for (int dt = 0; dt < 4; ++dt) {
        bf16x8 va = *reinterpret_cast<const bf16x8*>(&Vts[(dt * 16 + cl) * 72 + kc * 32 + g * 8]);
        oaccT[dt] = __builtin_amdgcn_mfma_f32_16x16x32_bf16(va, pa, oaccT[dt], 0, 0, 0);
      }
    }
    __syncthreads();
  }

  if (qrow < LSEQ) {
    float inv = 1.f / lrow;
#pragma unroll
    for (int dt = 0; dt < 4; ++dt) {
      ushort4 o4;
      o4.x = f2bf(oaccT[dt][0] * inv); o4.y = f2bf(oaccT[dt][1] * inv);
      o4.z = f2bf(oaccT[dt][2] * inv); o4.w = f2bf(oaccT[dt][3] * inv);
      *reinterpret_cast<ushort4*>(
          &y[((size_t)nb * LSEQ + qrow) * CD + h * HD + dt * 16 + g * 4]) = o4;
    }
  }
}

// ---------------- K3: depthwise 3x3 conv (reads V^T), add into y ------------
__global__ __launch_bounds__(256) void dwc_add(
    const u16* __restrict__ vt, const float* __restrict__ wd,
    const float* __restrict__ bd, u16* __restrict__ y) {
  __shared__ u16 V[32 * 588];
  const int d0 = blockIdx.x * 32;
  const int h = blockIdx.y;
  const int nb = blockIdx.z;
  const int t = threadIdx.x;
  const u16* vrow = vt + (((size_t)nb * NH + h) * HD + d0) * LPAD;

  for (int c = t; c < 32 * 73; c += 256) {
    int row = c / 73;
    int k0 = (c - row * 73) * 8;
    uint4 vv = *reinterpret_cast<const uint4*>(vrow + (size_t)row * LPAD + k0);
    const u16* vp = (const u16*)&vv;
    *reinterpret_cast<ushort4*>(&V[row * 588 + k0]) = *(const ushort4*)vp;
    *reinterpret_cast<ushort4*>(&V[row * 588 + k0 + 4]) = *(const ushort4*)(vp + 4);
  }
  __syncthreads();

  const int d = t & 31;
  const int c = h * HD + d0 + d;
  float w9[9];
#pragma unroll
  for (int j = 0; j < 9; ++j) w9[j] = wd[c * 9 + j];
  const float bias = bd[c];
  const u16* Vd = &V[d * 588];

  for (int it = 0; it < 72; ++it) {
    int li = (t >> 5) + it * 8;
    int py = li / 24, px = li - py * 24;
    float acc = bias;
#pragma unroll
    for (int ky = 0; ky < 3; ++ky) {
      int yy = py + ky - 1;
      if (yy < 0 || yy >= 24) continue;
      int base = 1 + yy * 24;
#pragma unroll
      for (int kx = 0; kx < 3; ++kx) {
        int xx = px + kx - 1;
        if (xx < 0 || xx >= 24) continue;
        acc += w9[ky * 3 + kx] * bf2f(Vd[base + xx]);
      }
    }
    size_t yi = ((size_t)nb * LSEQ + 1 + li) * CD + c;
    y[yi] = f2bf(bf2f(y[yi]) + acc);
  }
}

// ---------------- K4: proj GEMM (M=18464, N=768, K=768), 128^2 2-phase ------
__global__ __launch_bounds__(256) void proj_gemm(
    const u16* __restrict__ yb, const u16* __restrict__ wpb,
    const float* __restrict__ bias, float* __restrict__ out) {
  __shared__ __align__(16) u16 As[2][128 * 32];
  __shared__ __align__(16) u16 Bs[2][128 * 32];
  const int m0 = blockIdx.x * 128;
  const int n0 = blockIdx.y * 128;
  const int t = threadIdx.x;
  const int lane = t & 63, wid = t >> 6;
  const int wm = wid >> 1, wn = wid & 1;
  const int g = lane >> 4, cl = lane & 15;

  const int srow = wid * 32 + (lane >> 2);
  const int scol = (lane & 3) * 8;
  int ga0 = m0 + srow;      ga0 = ga0 < MROWS ? ga0 : MROWS - 1;
  int ga1 = m0 + srow + 16; ga1 = ga1 < MROWS ? ga1 : MROWS - 1;
  const u16* asrc0 = yb + (size_t)ga0 * CD + scol;
  const u16* asrc1 = yb + (size_t)ga1 * CD + scol;
  const u16* bsrc0 = wpb + (size_t)(n0 + srow) * CD + scol;
  const u16* bsrc1 = wpb + (size_t)(n0 + srow + 16) * CD + scol;

  const f32x4 fz = {0.f, 0.f, 0.f, 0.f};
  f32x4 acc[4][4];
#pragma unroll
  for (int i = 0; i < 4; ++i)
#pragma unroll
    for (int j = 0; j < 4; ++j) acc[i][j] = fz;

#define PSTAGE(b, kt)                                   \
  do {                                                  \
    int kc = (kt) * 32;                                 \
    GLD16(asrc0 + kc, &As[b][wid * 1024]);              \
    GLD16(asrc1 + kc, &As[b][wid * 1024 + 512]);        \
    GLD16(bsrc0 + kc, &Bs[b][wid * 1024]);              \
    GLD16(bsrc1 + kc, &Bs[b][wid * 1024 + 512]);        \
  } while (0)

  PSTAGE(0, 0);
  __syncthreads();
  int cur = 0;
  for (int kt = 0; kt < 24; ++kt) {
    if (kt < 23) PSTAGE(cur ^ 1, kt + 1);
    bf16x8 af[4], bfv[4];
#pragma unroll
    for (int mt = 0; mt < 4; ++mt)
      af[mt] = *reinterpret_cast<const bf16x8*>(&As[cur][(wm * 64 + mt * 16 + cl) * 32 + g * 8]);
#pragma unroll
    for (int nt = 0; nt < 4; ++nt)
      bfv[nt] = *reinterpret_cast<const bf16x8*>(&Bs[cur][(wn * 64 + nt * 16 + cl) * 32 + g * 8]);
    __builtin_amdgcn_s_setprio(1);
#pragma unroll
    for (int mt = 0; mt < 4; ++mt)
#pragma unroll
      for (int nt = 0; nt < 4; ++nt)
        acc[mt][nt] = __builtin_amdgcn_mfma_f32_16x16x32_bf16(af[mt], bfv[nt], acc[mt][nt], 0, 0, 0);
    __builtin_amdgcn_s_setprio(0);
    __syncthreads();
    cur ^= 1;
  }
#undef PSTAGE

#pragma unroll
  for (int nt = 0; nt < 4; ++nt) {
    int n = n0 + wn * 64 + nt * 16 + cl;
    float bn = bias[n];
#pragma unroll
    for (int mt = 0; mt < 4; ++mt)
#pragma unroll
      for (int r = 0; r < 4; ++r) {
        int m = m0 + wm * 64 + mt * 16 + g * 4 + r;
        if (m < MROWS) out[(size_t)m * CD + n] = acc[mt][nt][r] + bn;
      }
  }
}

extern "C" void kernel_launch(void* const* d_in, const int* in_sizes, int n_in,
                              void* d_out, int out_size, void* d_ws, size_t ws_size,
                              hipStream_t stream) {
  const float* x = (const float*)d_in[0];
  const float* w_qkv = (const float*)d_in[1];
  const float* w_proj = (const float*)d_in[2];
  const float* b_proj = (const float*)d_in[3];
  const float* w_dwc = (const float*)d_in[4];
  const float* b_dwc = (const float*)d_in[5];
  float* out = (float*)d_out;

  const size_t SEG = (size_t)NB * NH * LSEQ * HD;   // 14,180,352
  const size_t SEGT = (size_t)NB * NH * HD * LPAD;  // 14,352,384
  const size_t YN = (size_t)MROWS * CD;             // 14,180,352
  u16* yb = (u16*)d_ws;          // aliases xb: x needed only by qkv (before y)
  u16* xb = yb;
  u16* qb = yb + YN;
  u16* kb = qb + SEG;
  u16* vtb = kb + SEG;
  u16* wqb = vtb + SEGT;
  u16* wpb = wqb + (size_t)3 * CD * CD;

  cvt_bf16<<<dim3((int)(YN / 4 / 256)), 256, 0, stream>>>(x, xb, (int)(YN / 4));
  cvt_bf16<<<dim3(3 * CD * CD / 4 / 256), 256, 0, stream>>>(w_qkv, wqb, 3 * CD * CD / 4);
  cvt_bf16<<<dim3(CD * CD / 4 / 256), 256, 0, stream>>>(w_proj, wpb, CD * CD / 4);
  qkv_gemm<<<dim3(73, 9), 512, 0, stream>>>(xb, wqb, qb, kb, vtb);
  attn_fwd<<<dim3(5, 12, 32), 512, 0, stream>>>(qb, kb, vtb, yb);
  dwc_add<<<dim3(2, 12, 32), 256, 0, stream>>>(vtb, w_dwc, b_dwc, yb);
  proj_gemm<<<dim3(145, 6), 256, 0, stream>>>(yb, wpb, b_proj, out);
}

// Round 7
// 354.506 us; speedup vs baseline: 1.5734x; 1.1124x over previous
//
#include <hip/hip_runtime.h>

typedef short bf16x8 __attribute__((ext_vector_type(8)));
typedef float f32x4 __attribute__((ext_vector_type(4)));
typedef unsigned short u16;
typedef __attribute__((address_space(3))) const u16* lds_cptr;

#define NB 32
#define LSEQ 577
#define CD 768
#define NH 12
#define HD 64
#define MROWS (NB * LSEQ)  // 18464
#define LPAD 584           // V^T row pad (multiple of 8 for aligned uint4)

#define GLD16(g, l)                                                    \
  __builtin_amdgcn_global_load_lds(                                    \
      (const __attribute__((address_space(1))) void*)(g),              \
      (__attribute__((address_space(3))) void*)(l), 16, 0, 0)

// inline-asm LDS read: invisible to the memory legalizer, so no spurious
// vmcnt(0) is inserted against in-flight global_load_lds (rule #18 pattern).
#define DSR(dst, base, ofs)                                            \
  asm volatile("ds_read_b128 %0, %1 offset:" #ofs                      \
               : "=v"(dst) : "v"((lds_cptr)(base)))

__device__ __forceinline__ u16 f2bf(float f) {
  union { float f; unsigned u; } v; v.f = f;
  unsigned u = v.u + 0x7fffu + ((v.u >> 16) & 1u);  // RNE
  return (u16)(u >> 16);
}
__device__ __forceinline__ float bf2f(u16 s) {
  union { unsigned u; float f; } v; v.u = ((unsigned)s) << 16;
  return v.f;
}

// ---------------- K0: fp32 -> bf16 conversion (vectorized, memory-bound) ----
__global__ __launch_bounds__(256) void cvt_bf16(
    const float* __restrict__ src, u16* __restrict__ dst, int n4) {
  int i = blockIdx.x * 256 + threadIdx.x;
  if (i < n4) {
    float4 v = reinterpret_cast<const float4*>(src)[i];
    ushort4 o;
    o.x = f2bf(v.x); o.y = f2bf(v.y); o.z = f2bf(v.z); o.w = f2bf(v.w);
    reinterpret_cast<ushort4*>(dst)[i] = o;
  }
}

// ---------------- K1: QKV GEMM (M=18464, N=2304, K=768) ---------------------
// 256^2, BK=32, 8 waves. 3-buf circular LDS, depth-2 prefetch, vmcnt(4),
// inline-asm ds_read fragments (no compiler alias-waits). XCD-swizzled grid.
__global__ __launch_bounds__(512, 2) void qkv_gemm(
    const u16* __restrict__ xb, const u16* __restrict__ wqb,
    u16* __restrict__ qb, u16* __restrict__ kb, u16* __restrict__ vtb) {
  __shared__ __align__(16) u16 As[3][256 * 32];
  __shared__ __align__(16) u16 Bs[3][256 * 32];
  // bijective XCD swizzle over 657 blocks (657 = 8*82+1); n-fast tile order
  const int id = blockIdx.x;
  const int xcd = id & 7, pos = id >> 3;
  const int wg = (xcd == 0 ? pos : 83 + (xcd - 1) * 82 + pos);
  const int m0 = (wg / 9) * 256;
  const int n0 = (wg % 9) * 256;
  const int t = threadIdx.x;
  const int lane = t & 63, wid = t >> 6;          // 8 waves
  const int wm = wid >> 2, wn = wid & 3;          // 2 x 4 wave grid
  const int g = lane >> 4, cl = lane & 15;

  const int r16 = lane >> 2;
  const int scol = (lane & 3) * 8;
  const int ra0 = wid * 16 + r16;
  const int ra1 = 128 + wid * 16 + r16;
  int gm0 = m0 + ra0; gm0 = gm0 < MROWS ? gm0 : MROWS - 1;
  int gm1 = m0 + ra1; gm1 = gm1 < MROWS ? gm1 : MROWS - 1;
  const u16* ax0 = xb + (size_t)gm0 * CD + scol;
  const u16* ax1 = xb + (size_t)gm1 * CD + scol;
  const u16* bx0 = wqb + (size_t)(n0 + ra0) * CD + scol;
  const u16* bx1 = wqb + (size_t)(n0 + ra1) * CD + scol;

  const f32x4 fz = {0.f, 0.f, 0.f, 0.f};
  f32x4 acc[8][4];
#pragma unroll
  for (int i = 0; i < 8; ++i)
#pragma unroll
    for (int j = 0; j < 4; ++j) acc[i][j] = fz;

#define QSTAGE(b, kt)                                  \
  do {                                                 \
    int kc = (kt) * 32;                                \
    GLD16(ax0 + kc, &As[b][wid * 512]);                \
    GLD16(ax1 + kc, &As[b][(wid + 8) * 512]);          \
    GLD16(bx0 + kc, &Bs[b][wid * 512]);                \
    GLD16(bx1 + kc, &Bs[b][(wid + 8) * 512]);          \
  } while (0)

  QSTAGE(0, 0);
  QSTAGE(1, 1);
  for (int kt = 0; kt < 24; ++kt) {
    const int cb = kt % 3;
    if (kt < 23) asm volatile("s_waitcnt vmcnt(4)");
    else         asm volatile("s_waitcnt vmcnt(0)");
    __builtin_amdgcn_s_barrier();
    if (kt < 22) QSTAGE((kt + 2) % 3, kt + 2);
    const u16* pa = &As[cb][(wm * 128 + cl) * 32 + g * 8];
    const u16* pb = &Bs[cb][(wn * 64 + cl) * 32 + g * 8];
    bf16x8 af[8], bfv[4];
    DSR(af[0], pa, 0);    DSR(af[1], pa, 1024);
    DSR(af[2], pa, 2048); DSR(af[3], pa, 3072);
    DSR(af[4], pa, 4096); DSR(af[5], pa, 5120);
    DSR(af[6], pa, 6144); DSR(af[7], pa, 7168);
    DSR(bfv[0], pb, 0);    DSR(bfv[1], pb, 1024);
    DSR(bfv[2], pb, 2048); DSR(bfv[3], pb, 3072);
    asm volatile("s_waitcnt lgkmcnt(0)");
    __builtin_amdgcn_sched_barrier(0);
    __builtin_amdgcn_s_setprio(1);
#pragma unroll
    for (int mt = 0; mt < 8; ++mt)
#pragma unroll
      for (int nt = 0; nt < 4; ++nt)
        acc[mt][nt] = __builtin_amdgcn_mfma_f32_16x16x32_bf16(af[mt], bfv[nt], acc[mt][nt], 0, 0, 0);
    __builtin_amdgcn_s_setprio(0);
  }
#undef QSTAGE

  const int which = n0 / CD;          // uniform per block: 0=q, 1=k, 2=v
  const int rem0 = n0 % CD;
#pragma unroll
  for (int mt = 0; mt < 8; ++mt) {
#pragma unroll
    for (int nt = 0; nt < 4; ++nt) {
      int rem = rem0 + wn * 64 + nt * 16 + cl;
      int hh = rem >> 6, d = rem & 63;
#pragma unroll
      for (int r = 0; r < 4; ++r) {
        int m = m0 + wm * 128 + mt * 16 + g * 4 + r;
        if (m < MROWS) {
          int nb = m / LSEQ, l = m - nb * LSEQ;
          if (which == 0)
            qb[(((size_t)nb * NH + hh) * LSEQ + l) * HD + d] = f2bf(acc[mt][nt][r] * 0.125f);
          else if (which == 1)
            kb[(((size_t)nb * NH + hh) * LSEQ + l) * HD + d] = f2bf(acc[mt][nt][r]);
          else
            vtb[(((size_t)nb * NH + hh) * HD + d) * LPAD + l] = f2bf(acc[mt][nt][r]);
        }
      }
    }
  }
}

// ---------------- K2: flash attention (swapped S^T/O^T), dbuf + prefetch ----
// block = (qtile of 128 rows, head, batch); 8 waves; ONE barrier per KV tile
// (Ps is wave-private -> no publish barrier needed).
__global__ __launch_bounds__(512) void attn_fwd(
    const u16* __restrict__ q, const u16* __restrict__ k,
    const u16* __restrict__ vt, u16* __restrict__ y) {
  __shared__ __align__(16) u16 Ks[2][64 * 72];    // [kk][d]
  __shared__ __align__(16) u16 Vts[2][64 * 72];   // [d][kk]
  __shared__ __align__(16) u16 Ps[8][16 * 72];    // per-wave P [q][kk]

  const int qtile = blockIdx.x;
  const int h = blockIdx.y;
  const int nb = blockIdx.z;
  const int tid = threadIdx.x;
  const int lane = tid & 63, wid = tid >> 6;
  const int g = lane >> 4, cl = lane & 15;

  const size_t hoff = ((size_t)nb * NH + h) * LSEQ * HD;
  const u16* qh = q + hoff;
  const u16* kh = k + hoff;
  const u16* vth = vt + ((size_t)nb * NH + h) * HD * LPAD;

  const int qbase = qtile * 128;
  const int qrow = qbase + wid * 16 + cl;
  const int qrc = qrow < LSEQ ? qrow : LSEQ - 1;
  bf16x8 qf0 = *reinterpret_cast<const bf16x8*>(qh + (size_t)qrc * HD + g * 8);
  bf16x8 qf1 = *reinterpret_cast<const bf16x8*>(qh + (size_t)qrc * HD + 32 + g * 8);

  const f32x4 fz = {0.f, 0.f, 0.f, 0.f};
  float mrow = -3.0e38f, lrow = 0.f;
  f32x4 oaccT[4];
#pragma unroll
  for (int dt = 0; dt < 4; ++dt) oaccT[dt] = fz;

  // staging geometry: 512 threads cover 64 rows x 8 chunks of 8 elems
  const int srow = tid >> 3, sc8 = (tid & 7) << 3;
  const u16* kptr = kh + (size_t)srow * HD + sc8;
  const u16* vptr = vth + (size_t)srow * LPAD + sc8;

  // prologue: tile 0 (rows 0..63 all < LSEQ)
  {
    uint4 kd = *reinterpret_cast<const uint4*>(kptr);
    uint4 vd = *reinterpret_cast<const uint4*>(vptr);
    *reinterpret_cast<uint4*>(&Ks[0][srow * 72 + sc8]) = kd;
    *reinterpret_cast<uint4*>(&Vts[0][srow * 72 + sc8]) = vd;
  }
  __syncthreads();

  const int NT = 10;  // ceil(577/64)
  for (int tt = 0; tt < NT; ++tt) {
    const int c = tt & 1;
    const int kv = tt * 64;
    // T14: issue next tile's loads (hidden under QK^T + softmax + PV)
    uint4 kn = {0, 0, 0, 0}, vn = {0, 0, 0, 0};
    const bool pre = (tt + 1 < NT);
    if (pre) {
      int grow = kv + 64 + srow;
      if (grow < LSEQ) kn = *reinterpret_cast<const uint4*>(kptr + (size_t)(kv + 64) * HD);
      vn = *reinterpret_cast<const uint4*>(vptr + (kv + 64));
    }

    // S^T = K Q^T
    f32x4 sT[4];
    __builtin_amdgcn_s_setprio(1);
#pragma unroll
    for (int nt = 0; nt < 4; ++nt) {
      bf16x8 a0 = *reinterpret_cast<const bf16x8*>(&Ks[c][(nt * 16 + cl) * 72 + g * 8]);
      bf16x8 a1 = *reinterpret_cast<const bf16x8*>(&Ks[c][(nt * 16 + cl) * 72 + 32 + g * 8]);
      f32x4 s = fz;
      s = __builtin_amdgcn_mfma_f32_16x16x32_bf16(a0, qf0, s, 0, 0, 0);
      s = __builtin_amdgcn_mfma_f32_16x16x32_bf16(a1, qf1, s, 0, 0, 0);
      sT[nt] = s;
    }
    __builtin_amdgcn_s_setprio(0);

#pragma unroll
    for (int nt = 0; nt < 4; ++nt)
#pragma unroll
      for (int r = 0; r < 4; ++r)
        if (kv + nt * 16 + g * 4 + r >= LSEQ) sT[nt][r] = -3.0e38f;

    float pm = -3.0e38f;
#pragma unroll
    for (int nt = 0; nt < 4; ++nt)
#pragma unroll
      for (int r = 0; r < 4; ++r) pm = fmaxf(pm, sT[nt][r]);
    pm = fmaxf(pm, __shfl_xor(pm, 16));
    pm = fmaxf(pm, __shfl_xor(pm, 32));

    float nm = fmaxf(mrow, pm);
    float alpha = __expf(mrow - nm);
    mrow = nm;
    float ps = 0.f;
#pragma unroll
    for (int nt = 0; nt < 4; ++nt)
#pragma unroll
      for (int r = 0; r < 4; ++r) {
        float p = __expf(sT[nt][r] - nm);
        sT[nt][r] = p;
        ps += p;
      }
    ps += __shfl_xor(ps, 16);
    ps += __shfl_xor(ps, 32);
    lrow = lrow * alpha + ps;
#pragma unroll
    for (int dt = 0; dt < 4; ++dt) oaccT[dt] *= alpha;

    // P -> wave-private LDS (no barrier needed; in-wave lgkm ordering only)
#pragma unroll
    for (int nt = 0; nt < 4; ++nt) {
      ushort4 p4;
      p4.x = f2bf(sT[nt][0]); p4.y = f2bf(sT[nt][1]);
      p4.z = f2bf(sT[nt][2]); p4.w = f2bf(sT[nt][3]);
      *reinterpret_cast<ushort4*>(&Ps[wid][cl * 72 + nt * 16 + g * 4]) = p4;
    }

    // O^T += V^T P^T
    __builtin_amdgcn_s_setprio(1);
#pragma unroll
    for (int kc = 0; kc < 2; ++kc) {
      bf16x8 pa = *reinterpret_cast<const bf16x8*>(&Ps[wid][cl * 72 + kc * 32 + g * 8]);
#pragma unroll
      for (int dt = 0; dt < 4; ++dt) {
        bf16x8 va = *reinterpret_cast<const bf16x8*>(&Vts[c][(dt * 16 + cl) * 72 + kc * 32 + g * 8]);
        oaccT[dt] = __builtin_amdgcn_mfma_f32_16x16x32_bf16(va, pa, oaccT[dt], 0, 0, 0);
      }
    }
    __builtin_amdgcn_s_setprio(0);

    // write prefetched tile into the other buffer (nobody reads it now)
    if (pre) {
      *reinterpret_cast<uint4*>(&Ks[c ^ 1][srow * 72 + sc8]) = kn;
      *reinterpret_cast<uint4*>(&Vts[c ^ 1][srow * 72 + sc8]) = vn;
    }
    __syncthreads();   // publish buf c^1; also proves all reads of buf c done
  }

  if (qrow < LSEQ) {
    float inv = 1.f / lrow;
#pragma unroll
    for (int dt = 0; dt < 4; ++dt) {
      ushort4 o4;
      o4.x = f2bf(oaccT[dt][0] * inv); o4.y = f2bf(oaccT[dt][1] * inv);
      o4.z = f2bf(oaccT[dt][2] * inv); o4.w = f2bf(oaccT[dt][3] * inv);
      *reinterpret_cast<ushort4*>(
          &y[((size_t)nb * LSEQ + qrow) * CD + h * HD + dt * 16 + g * 4]) = o4;
    }
  }
}

// ---------------- K3: depthwise 3x3 conv (reads V^T), add into y ------------
__global__ __launch_bounds__(256) void dwc_add(
    const u16* __restrict__ vt, const float* __restrict__ wd,
    const float* __restrict__ bd, u16* __restrict__ y) {
  __shared__ u16 V[32 * 588];
  const int d0 = blockIdx.x * 32;
  const int h = blockIdx.y;
  const int nb = blockIdx.z;
  const int t = threadIdx.x;
  const u16* vrow = vt + (((size_t)nb * NH + h) * HD + d0) * LPAD;

  for (int c = t; c < 32 * 73; c += 256) {
    int row = c / 73;
    int k0 = (c - row * 73) * 8;
    uint4 vv = *reinterpret_cast<const uint4*>(vrow + (size_t)row * LPAD + k0);
    const u16* vp = (const u16*)&vv;
    *reinterpret_cast<ushort4*>(&V[row * 588 + k0]) = *(const ushort4*)vp;
    *reinterpret_cast<ushort4*>(&V[row * 588 + k0 + 4]) = *(const ushort4*)(vp + 4);
  }
  __syncthreads();

  const int d = t & 31;
  const int c = h * HD + d0 + d;
  float w9[9];
#pragma unroll
  for (int j = 0; j < 9; ++j) w9[j] = wd[c * 9 + j];
  const float bias = bd[c];
  const u16* Vd = &V[d * 588];

  for (int it = 0; it < 72; ++it) {
    int li = (t >> 5) + it * 8;
    int py = li / 24, px = li - py * 24;
    float acc = bias;
#pragma unroll
    for (int ky = 0; ky < 3; ++ky) {
      int yy = py + ky - 1;
      if (yy < 0 || yy >= 24) continue;
      int base = 1 + yy * 24;
#pragma unroll
      for (int kx = 0; kx < 3; ++kx) {
        int xx = px + kx - 1;
        if (xx < 0 || xx >= 24) continue;
        acc += w9[ky * 3 + kx] * bf2f(Vd[base + xx]);
      }
    }
    size_t yi = ((size_t)nb * LSEQ + 1 + li) * CD + c;
    y[yi] = f2bf(bf2f(y[yi]) + acc);
  }
}

// ---------------- K4: proj GEMM (M=18464, N=768, K=768), 128^2 2-phase ------
__global__ __launch_bounds__(256) void proj_gemm(
    const u16* __restrict__ yb, const u16* __restrict__ wpb,
    const float* __restrict__ bias, float* __restrict__ out) {
  __shared__ __align__(16) u16 As[2][128 * 32];
  __shared__ __align__(16) u16 Bs[2][128 * 32];
  // bijective XCD swizzle over 870 blocks (870 = 8*108+6); n-fast order
  const int id = blockIdx.x;
  const int xcd = id & 7, pos = id >> 3;
  const int wg = (xcd < 6 ? xcd * 109 + pos : 654 + (xcd - 6) * 108 + pos);
  const int m0 = (wg / 6) * 128;
  const int n0 = (wg % 6) * 128;
  const int t = threadIdx.x;
  const int lane = t & 63, wid = t >> 6;
  const int wm = wid >> 1, wn = wid & 1;
  const int g = lane >> 4, cl = lane & 15;

  const int srow = wid * 32 + (lane >> 2);
  const int scol = (lane & 3) * 8;
  int ga0 = m0 + srow;      ga0 = ga0 < MROWS ? ga0 : MROWS - 1;
  int ga1 = m0 + srow + 16; ga1 = ga1 < MROWS ? ga1 : MROWS - 1;
  const u16* asrc0 = yb + (size_t)ga0 * CD + scol;
  const u16* asrc1 = yb + (size_t)ga1 * CD + scol;
  const u16* bsrc0 = wpb + (size_t)(n0 + srow) * CD + scol;
  const u16* bsrc1 = wpb + (size_t)(n0 + srow + 16) * CD + scol;

  const f32x4 fz = {0.f, 0.f, 0.f, 0.f};
  f32x4 acc[4][4];
#pragma unroll
  for (int i = 0; i < 4; ++i)
#pragma unroll
    for (int j = 0; j < 4; ++j) acc[i][j] = fz;

#define PSTAGE(b, kt)                                   \
  do {                                                  \
    int kc = (kt) * 32;                                 \
    GLD16(asrc0 + kc, &As[b][wid * 1024]);              \
    GLD16(asrc1 + kc, &As[b][wid * 1024 + 512]);        \
    GLD16(bsrc0 + kc, &Bs[b][wid * 1024]);              \
    GLD16(bsrc1 + kc, &Bs[b][wid * 1024 + 512]);        \
  } while (0)

  PSTAGE(0, 0);
  __syncthreads();
  int cur = 0;
  for (int kt = 0; kt < 24; ++kt) {
    if (kt < 23) PSTAGE(cur ^ 1, kt + 1);
    bf16x8 af[4], bfv[4];
#pragma unroll
    for (int mt = 0; mt < 4; ++mt)
      af[mt] = *reinterpret_cast<const bf16x8*>(&As[cur][(wm * 64 + mt * 16 + cl) * 32 + g * 8]);
#pragma unroll
    for (int nt = 0; nt < 4; ++nt)
      bfv[nt] = *reinterpret_cast<const bf16x8*>(&Bs[cur][(wn * 64 + nt * 16 + cl) * 32 + g * 8]);
    __builtin_amdgcn_s_setprio(1);
#pragma unroll
    for (int mt = 0; mt < 4; ++mt)
#pragma unroll
      for (int nt = 0; nt < 4; ++nt)
        acc[mt][nt] = __builtin_amdgcn_mfma_f32_16x16x32_bf16(af[mt], bfv[nt], acc[mt][nt], 0, 0, 0);
    __builtin_amdgcn_s_setprio(0);
    __syncthreads();
    cur ^= 1;
  }
#undef PSTAGE

#pragma unroll
  for (int nt = 0; nt < 4; ++nt) {
    int n = n0 + wn * 64 + nt * 16 + cl;
    float bn = bias[n];
#pragma unroll
    for (int mt = 0; mt < 4; ++mt)
#pragma unroll
      for (int r = 0; r < 4; ++r) {
        int m = m0 + wm * 64 + mt * 16 + g * 4 + r;
        if (m < MROWS) out[(size_t)m * CD + n] = acc[mt][nt][r] + bn;
      }
  }
}

extern "C" void kernel_launch(void* const* d_in, const int* in_sizes, int n_in,
                              void* d_out, int out_size, void* d_ws, size_t ws_size,
                              hipStream_t stream) {
  const float* x = (const float*)d_in[0];
  const float* w_qkv = (const float*)d_in[1];
  const float* w_proj = (const float*)d_in[2];
  const float* b_proj = (const float*)d_in[3];
  const float* w_dwc = (const float*)d_in[4];
  const float* b_dwc = (const float*)d_in[5];
  float* out = (float*)d_out;

  const size_t SEG = (size_t)NB * NH * LSEQ * HD;   // 14,180,352
  const size_t SEGT = (size_t)NB * NH * HD * LPAD;  // 14,352,384
  const size_t YN = (size_t)MROWS * CD;             // 14,180,352
  u16* yb = (u16*)d_ws;          // aliases xb: x needed only by qkv (before y)
  u16* xb = yb;
  u16* qb = yb + YN;
  u16* kb = qb + SEG;
  u16* vtb = kb + SEG;
  u16* wqb = vtb + SEGT;
  u16* wpb = wqb + (size_t)3 * CD * CD;

  cvt_bf16<<<dim3((int)(YN / 4 / 256)), 256, 0, stream>>>(x, xb, (int)(YN / 4));
  cvt_bf16<<<dim3(3 * CD * CD / 4 / 256), 256, 0, stream>>>(w_qkv, wqb, 3 * CD * CD / 4);
  cvt_bf16<<<dim3(CD * CD / 4 / 256), 256, 0, stream>>>(w_proj, wpb, CD * CD / 4);
  qkv_gemm<<<dim3(657), 512, 0, stream>>>(xb, wqb, qb, kb, vtb);
  attn_fwd<<<dim3(5, 12, 32), 512, 0, stream>>>(qb, kb, vtb, yb);
  dwc_add<<<dim3(2, 12, 32), 256, 0, stream>>>(vtb, w_dwc, b_dwc, yb);
  proj_gemm<<<dim3(870), 256, 0, stream>>>(yb, wpb, b_proj, out);
}